// Round 1
// baseline (12344.850 us; speedup 1.0000x reference)
//
#include <hip/hip_runtime.h>

#define TOK  6304      // 32*197 valid token rows
#define MPAD 6400      // padded rows for 128-tiles
#define NH   12
#define HD   64
#define BHD  384       // 32*12 (b,h) pairs
#define NPD  256       // padded seq per head
#define QKVD 2304

typedef float  f32x4  __attribute__((ext_vector_type(4)));
typedef __bf16 bf16x8 __attribute__((ext_vector_type(8)));

__device__ __forceinline__ unsigned short f2bf(float f) {
  unsigned u = __float_as_uint(f);
  return (unsigned short)((u + 0x7fffu + ((u >> 16) & 1u)) >> 16);
}
__device__ __forceinline__ float bf2f(unsigned short h) {
  return __uint_as_float(((unsigned)h) << 16);
}

__device__ __forceinline__ void gl2lds16(void* g, void* l) {
  __builtin_amdgcn_global_load_lds((__attribute__((address_space(1))) void*)g,
                                   (__attribute__((address_space(3))) void*)l, 16, 0, 0);
}

// NT GEMM core: C[m,n] = sum_k A[m,k]*B[n,k], A/B bf16 K-contiguous.
// BM x BN tile, BK=32, 4 waves; wave grid (BM/16/MT) x (BN/16/NT), WC = BN/16/NT.
template<int BM, int BN, int MT, int NT, int WC>
__device__ __forceinline__ void gemm_core(const unsigned short* A, int lda,
                                          const unsigned short* B, int ldb,
                                          int K, int bm, int bn,
                                          unsigned short* lds,
                                          f32x4 (&acc)[MT][NT]) {
  const int tid  = threadIdx.x;
  const int wave = tid >> 6, lane = tid & 63;
  const int wr = wave / WC, wc = wave % WC;
  const int lh = lane >> 4, lm = lane & 15;
  unsigned short* ldsA = lds;
  unsigned short* ldsB = lds + BM * 32;
  constexpr int AIT = BM / 64, BIT = BN / 64;
  for (int k0 = 0; k0 < K; k0 += 32) {
    #pragma unroll
    for (int it = 0; it < AIT; ++it) {
      int idx16 = (wave * AIT + it) * 64 + lane;
      int row = idx16 >> 2, seg = idx16 & 3;
      gl2lds16((void*)(A + (long)(bm + row) * lda + k0 + seg * 8), ldsA + idx16 * 8);
    }
    #pragma unroll
    for (int it = 0; it < BIT; ++it) {
      int idx16 = (wave * BIT + it) * 64 + lane;
      int row = idx16 >> 2, seg = idx16 & 3;
      gl2lds16((void*)(B + (long)(bn + row) * ldb + k0 + seg * 8), ldsB + idx16 * 8);
    }
    __syncthreads();   // drains vmcnt for global_load_lds
    bf16x8 af[MT], bfr[NT];
    #pragma unroll
    for (int i = 0; i < MT; ++i)
      af[i] = *(const bf16x8*)(ldsA + (wr * MT * 16 + i * 16 + lm) * 32 + lh * 8);
    #pragma unroll
    for (int j = 0; j < NT; ++j)
      bfr[j] = *(const bf16x8*)(ldsB + (wc * NT * 16 + j * 16 + lm) * 32 + lh * 8);
    #pragma unroll
    for (int i = 0; i < MT; ++i)
      #pragma unroll
      for (int j = 0; j < NT; ++j)
        acc[i][j] = __builtin_amdgcn_mfma_f32_16x16x32_bf16(af[i], bfr[j], acc[i][j], 0, 0, 0);
    __syncthreads();   // protect LDS before next stage
  }
}

// ---------- small kernels ----------

__global__ __launch_bounds__(256) void k_cvt(const float4* __restrict__ s,
                                             ushort4* __restrict__ d, int n4) {
  int stride = gridDim.x * 256;
  for (int i = blockIdx.x * 256 + threadIdx.x; i < n4; i += stride) {
    float4 v = s[i];
    ushort4 o;
    o.x = f2bf(v.x); o.y = f2bf(v.y); o.z = f2bf(v.z); o.w = f2bf(v.w);
    d[i] = o;
  }
}

__global__ __launch_bounds__(256) void k_unfold(const float* __restrict__ x,
                                                unsigned short* __restrict__ xp) {
  int idx = blockIdx.x * 256 + threadIdx.x;
  if (idx >= 32 * 196 * 768) return;
  int f = idx % 768; int rest = idx / 768;
  int p = rest % 196; int b = rest / 196;
  int c = f >> 8, ij = f & 255, i = ij >> 4, j = ij & 15;
  int py = p / 14, px = p % 14;
  xp[idx] = f2bf(x[(((long)b * 3 + c) * 224 + py * 16 + i) * 224 + px * 16 + j]);
}

__global__ __launch_bounds__(256) void k_cls(const float* __restrict__ cls,
                                             const float* __restrict__ pos,
                                             float* __restrict__ t) {
  int i = blockIdx.x * 256 + threadIdx.x;  // 32*768
  int b = i / 768, d = i % 768;
  t[((long)(b * 197)) * 768 + d] = cls[d] + pos[d];
}

__global__ __launch_bounds__(256) void k_ln(const float* __restrict__ t,
                                            const float* __restrict__ gw,
                                            const float* __restrict__ bw,
                                            unsigned short* __restrict__ h) {
  __shared__ float red[4];
  int row = blockIdx.x, tid = threadIdx.x;
  const float* x = t + (long)row * 768;
  float v0 = x[tid], v1 = x[tid + 256], v2 = x[tid + 512];
  float s = v0 + v1 + v2;
  #pragma unroll
  for (int off = 32; off > 0; off >>= 1) s += __shfl_xor(s, off, 64);
  int wave = tid >> 6, lane = tid & 63;
  if (lane == 0) red[wave] = s;
  __syncthreads();
  s = red[0] + red[1] + red[2] + red[3];
  float mean = s * (1.f / 768.f);
  float d0 = v0 - mean, d1 = v1 - mean, d2 = v2 - mean;
  float s2 = d0 * d0 + d1 * d1 + d2 * d2;
  __syncthreads();
  #pragma unroll
  for (int off = 32; off > 0; off >>= 1) s2 += __shfl_xor(s2, off, 64);
  if (lane == 0) red[wave] = s2;
  __syncthreads();
  s2 = red[0] + red[1] + red[2] + red[3];
  float rstd = rsqrtf(s2 * (1.f / 768.f) + 1e-6f);
  unsigned short* hr = h + (long)row * 768;
  hr[tid]       = f2bf(d0 * rstd * gw[tid]       + bw[tid]);
  hr[tid + 256] = f2bf(d1 * rstd * gw[tid + 256] + bw[tid + 256]);
  hr[tid + 512] = f2bf(d2 * rstd * gw[tid + 512] + bw[tid + 512]);
}

__global__ __launch_bounds__(256) void k_lora(const unsigned short* __restrict__ h,
                                              const float* __restrict__ A,
                                              float* __restrict__ hA) {
  int row = blockIdx.x, tid = threadIdx.x;
  float a[8];
  #pragma unroll
  for (int r = 0; r < 8; ++r) a[r] = 0.f;
  const unsigned short* hr = h + (long)row * 768;
  for (int kx = tid; kx < 768; kx += 256) {
    float hv = bf2f(hr[kx]);
    const float* Ar = A + kx * 8;
    #pragma unroll
    for (int r = 0; r < 8; ++r) a[r] += hv * Ar[r];
  }
  #pragma unroll
  for (int r = 0; r < 8; ++r)
    for (int off = 32; off > 0; off >>= 1) a[r] += __shfl_xor(a[r], off, 64);
  __shared__ float red[32];
  int wave = tid >> 6, lane = tid & 63;
  if (lane == 0) {
    #pragma unroll
    for (int r = 0; r < 8; ++r) red[wave * 8 + r] = a[r];
  }
  __syncthreads();
  if (tid < 8) hA[(long)row * 8 + tid] = red[tid] + red[8 + tid] + red[16 + tid] + red[24 + tid];
}

__global__ __launch_bounds__(256) void k_head(const float* __restrict__ t,
                                              const float* __restrict__ ng,
                                              const float* __restrict__ nb,
                                              const float* __restrict__ hw,
                                              const float* __restrict__ hb,
                                              float* __restrict__ out) {
  __shared__ float xs[768];
  __shared__ float red[4];
  int b = blockIdx.x, tid = threadIdx.x;
  const float* x = t + ((long)(b * 197)) * 768;
  float v0 = x[tid], v1 = x[tid + 256], v2 = x[tid + 512];
  float s = v0 + v1 + v2;
  #pragma unroll
  for (int off = 32; off > 0; off >>= 1) s += __shfl_xor(s, off, 64);
  int wave = tid >> 6, lane = tid & 63;
  if (lane == 0) red[wave] = s;
  __syncthreads();
  s = red[0] + red[1] + red[2] + red[3];
  float mean = s * (1.f / 768.f);
  float d0 = v0 - mean, d1 = v1 - mean, d2 = v2 - mean;
  float s2 = d0 * d0 + d1 * d1 + d2 * d2;
  __syncthreads();
  #pragma unroll
  for (int off = 32; off > 0; off >>= 1) s2 += __shfl_xor(s2, off, 64);
  if (lane == 0) red[wave] = s2;
  __syncthreads();
  s2 = red[0] + red[1] + red[2] + red[3];
  float rstd = rsqrtf(s2 * (1.f / 768.f) + 1e-6f);
  xs[tid]       = d0 * rstd * ng[tid]       + nb[tid];
  xs[tid + 256] = d1 * rstd * ng[tid + 256] + nb[tid + 256];
  xs[tid + 512] = d2 * rstd * ng[tid + 512] + nb[tid + 512];
  __syncthreads();
  for (int n = tid; n < 100; n += 256) {
    const float* wr = hw + (long)n * 768;
    float acc = hb[n];
    for (int k2 = 0; k2 < 768; ++k2) acc += xs[k2] * wr[k2];
    out[b * 100 + n] = acc;
  }
}

// ---------- GEMM wrappers ----------

__global__ __launch_bounds__(256) void k_patch_gemm(
    const unsigned short* __restrict__ xp, const unsigned short* __restrict__ w,
    const float* __restrict__ bias, const float* __restrict__ pos,
    float* __restrict__ t) {
  __shared__ unsigned short lds[(128 + 128) * 32];
  f32x4 acc[4][4] = {};
  int bm = blockIdx.x * 128, bn = blockIdx.y * 128;
  gemm_core<128, 128, 4, 4, 2>(xp, 768, w, 768, 768, bm, bn, lds, acc);
  const int wave = threadIdx.x >> 6, lane = threadIdx.x & 63;
  const int wr = wave >> 1, wc = wave & 1, lh = lane >> 4, lm = lane & 15;
  #pragma unroll
  for (int i = 0; i < 4; ++i)
  #pragma unroll
  for (int r = 0; r < 4; ++r) {
    int m = bm + wr * 64 + i * 16 + lh * 4 + r;
    int b = m / 196, p = m % 196;
    long trow = ((long)(b * 197 + 1 + p)) * 768;
    #pragma unroll
    for (int j = 0; j < 4; ++j) {
      int n = bn + wc * 64 + j * 16 + lm;
      t[trow + n] = acc[i][j][r] + bias[n] + pos[(1 + p) * 768 + n];
    }
  }
}

__global__ __launch_bounds__(256) void k_qkv(
    const unsigned short* __restrict__ h, const unsigned short* __restrict__ w,
    const float* __restrict__ bias, const float* __restrict__ hA,
    const float* __restrict__ loraB,
    unsigned short* __restrict__ q, unsigned short* __restrict__ kk,
    unsigned short* __restrict__ vT) {
  __shared__ unsigned short lds[(128 + 128) * 32];
  f32x4 acc[4][4] = {};
  int bm = blockIdx.x * 128, bn = blockIdx.y * 128;
  gemm_core<128, 128, 4, 4, 2>(h, 768, w, 768, 768, bm, bn, lds, acc);
  const int wave = threadIdx.x >> 6, lane = threadIdx.x & 63;
  const int wr = wave >> 1, wc = wave & 1, lh = lane >> 4, lm = lane & 15;
  for (int i = 0; i < 4; ++i)
  for (int r = 0; r < 4; ++r) {
    int m = bm + wr * 64 + i * 16 + lh * 4 + r;
    if (m >= TOK) continue;
    int b = m / 197, tok = m % 197;
    const float* ha = hA + (long)m * 8;
    #pragma unroll
    for (int j = 0; j < 4; ++j) {
      int n = bn + wc * 64 + j * 16 + lm;
      float lora = 0.f;
      #pragma unroll
      for (int rr = 0; rr < 8; ++rr) lora += ha[rr] * loraB[rr * QKVD + n];
      float v = acc[i][j][r] + bias[n] + 2.0f * lora;
      int which = n / 768;
      int nr = n - which * 768;
      int hh = nr >> 6, dd = nr & 63;
      long base = (long)(b * NH + hh);
      unsigned short bv = f2bf(v);
      if (which == 0)      q [(base * NPD + tok) * HD + dd] = bv;
      else if (which == 1) kk[(base * NPD + tok) * HD + dd] = bv;
      else                 vT[(base * HD + dd) * NPD + tok] = bv;
    }
  }
}

__global__ __launch_bounds__(256) void k_attn_s(
    const unsigned short* __restrict__ q, const unsigned short* __restrict__ kk,
    unsigned short* __restrict__ P) {
  __shared__ unsigned short lds[(128 + 256) * 32];
  f32x4 acc[2][16] = {};
  int bh = blockIdx.y;
  const unsigned short* Q = q  + (long)bh * NPD * HD;
  const unsigned short* K_ = kk + (long)bh * NPD * HD;
  gemm_core<128, 256, 2, 16, 1>(Q, HD, K_, HD, HD, blockIdx.x * 128, 0, lds, acc);
  const int wave = threadIdx.x >> 6, lane = threadIdx.x & 63;
  const int lh = lane >> 4, lm = lane & 15;
  long Pbase = (long)bh * NPD * NPD;
  for (int i = 0; i < 2; ++i) {
    for (int r = 0; r < 4; ++r) {
      float sv[16]; float mx = -3e38f;
      #pragma unroll
      for (int j = 0; j < 16; ++j) {
        float s = acc[i][j][r] * 0.125f;          // HD^-0.5
        if (j * 16 + lm >= 197) s = -3e38f;       // mask padded keys
        sv[j] = s; mx = fmaxf(mx, s);
      }
      #pragma unroll
      for (int off = 1; off < 16; off <<= 1) mx = fmaxf(mx, __shfl_xor(mx, off, 64));
      float sum = 0.f;
      #pragma unroll
      for (int j = 0; j < 16; ++j) {
        float e = (sv[j] < -1e38f) ? 0.f : __expf(sv[j] - mx);
        sv[j] = e; sum += e;
      }
      #pragma unroll
      for (int off = 1; off < 16; off <<= 1) sum += __shfl_xor(sum, off, 64);
      float inv = 1.f / sum;
      int row = blockIdx.x * 128 + wave * 32 + i * 16 + lh * 4 + r;
      long rowb = Pbase + (long)row * NPD + lm;
      #pragma unroll
      for (int j = 0; j < 16; ++j) P[rowb + j * 16] = f2bf(sv[j] * inv);
    }
  }
}

__global__ __launch_bounds__(256) void k_attn_pv(
    const unsigned short* __restrict__ P, const unsigned short* __restrict__ vT,
    unsigned short* __restrict__ o) {
  __shared__ unsigned short lds[(128 + 64) * 32];
  f32x4 acc[2][4] = {};
  int bh = blockIdx.y;
  int b = bh / NH, hh = bh % NH;
  gemm_core<128, 64, 2, 4, 1>(P + (long)bh * NPD * NPD, NPD,
                              vT + (long)bh * HD * NPD, NPD,
                              NPD, blockIdx.x * 128, 0, lds, acc);
  const int wave = threadIdx.x >> 6, lane = threadIdx.x & 63;
  const int lh = lane >> 4, lm = lane & 15;
  for (int i = 0; i < 2; ++i)
  for (int r = 0; r < 4; ++r) {
    int m = blockIdx.x * 128 + wave * 32 + i * 16 + lh * 4 + r;
    if (m >= 197) continue;
    long ob = ((long)(b * 197 + m)) * 768 + hh * 64;
    #pragma unroll
    for (int j = 0; j < 4; ++j) o[ob + j * 16 + lm] = f2bf(acc[i][j][r]);
  }
}

__global__ __launch_bounds__(256) void k_proj(
    const unsigned short* __restrict__ o, const unsigned short* __restrict__ w,
    const float* __restrict__ bias, float* __restrict__ t) {
  __shared__ unsigned short lds[(128 + 128) * 32];
  f32x4 acc[4][4] = {};
  int bm = blockIdx.x * 128, bn = blockIdx.y * 128;
  gemm_core<128, 128, 4, 4, 2>(o, 768, w, 768, 768, bm, bn, lds, acc);
  const int wave = threadIdx.x >> 6, lane = threadIdx.x & 63;
  const int wr = wave >> 1, wc = wave & 1, lh = lane >> 4, lm = lane & 15;
  for (int i = 0; i < 4; ++i)
  for (int r = 0; r < 4; ++r) {
    int m = bm + wr * 64 + i * 16 + lh * 4 + r;
    if (m >= TOK) continue;
    long trow = (long)m * 768;
    #pragma unroll
    for (int j = 0; j < 4; ++j) {
      int n = bn + wc * 64 + j * 16 + lm;
      t[trow + n] = acc[i][j][r] + bias[n] + t[trow + n];
    }
  }
}

__global__ __launch_bounds__(256) void k_fc1(
    const unsigned short* __restrict__ h, const unsigned short* __restrict__ w,
    const float* __restrict__ bias, unsigned short* __restrict__ g) {
  __shared__ unsigned short lds[(128 + 128) * 32];
  f32x4 acc[4][4] = {};
  int bm = blockIdx.x * 128, bn = blockIdx.y * 128;
  gemm_core<128, 128, 4, 4, 2>(h, 768, w, 768, 768, bm, bn, lds, acc);
  const int wave = threadIdx.x >> 6, lane = threadIdx.x & 63;
  const int wr = wave >> 1, wc = wave & 1, lh = lane >> 4, lm = lane & 15;
  for (int i = 0; i < 4; ++i)
  for (int r = 0; r < 4; ++r) {
    int m = bm + wr * 64 + i * 16 + lh * 4 + r;
    if (m >= TOK) continue;
    long grow = (long)m * 3072;
    #pragma unroll
    for (int j = 0; j < 4; ++j) {
      int n = bn + wc * 64 + j * 16 + lm;
      float u = acc[i][j][r] + bias[n];
      float ge = 0.5f * u * (1.f + erff(u * 0.70710678118654752440f));
      g[grow + n] = f2bf(ge);
    }
  }
}

__global__ __launch_bounds__(256) void k_fc2(
    const unsigned short* __restrict__ g, const unsigned short* __restrict__ w,
    const float* __restrict__ bias, float* __restrict__ t) {
  __shared__ unsigned short lds[(128 + 128) * 32];
  f32x4 acc[4][4] = {};
  int bm = blockIdx.x * 128, bn = blockIdx.y * 128;
  gemm_core<128, 128, 4, 4, 2>(g, 3072, w, 3072, 3072, bm, bn, lds, acc);
  const int wave = threadIdx.x >> 6, lane = threadIdx.x & 63;
  const int wr = wave >> 1, wc = wave & 1, lh = lane >> 4, lm = lane & 15;
  for (int i = 0; i < 4; ++i)
  for (int r = 0; r < 4; ++r) {
    int m = bm + wr * 64 + i * 16 + lh * 4 + r;
    if (m >= TOK) continue;
    long trow = (long)m * 768;
    #pragma unroll
    for (int j = 0; j < 4; ++j) {
      int n = bn + wc * 64 + j * 16 + lm;
      t[trow + n] = acc[i][j][r] + bias[n] + t[trow + n];
    }
  }
}

// ---------- host ----------

extern "C" void kernel_launch(void* const* d_in, const int* in_sizes, int n_in,
                              void* d_out, int out_size, void* d_ws, size_t ws_size,
                              hipStream_t stream) {
  const float* x       = (const float*)d_in[0];
  const float* patch_w = (const float*)d_in[1];
  const float* patch_b = (const float*)d_in[2];
  const float* cls_tok = (const float*)d_in[3];
  const float* pos     = (const float*)d_in[4];
  const float* ln1_g   = (const float*)d_in[5];
  const float* ln1_b   = (const float*)d_in[6];
  const float* qkv_w   = (const float*)d_in[7];
  const float* qkv_b   = (const float*)d_in[8];
  const float* lora_A  = (const float*)d_in[9];
  const float* lora_B  = (const float*)d_in[10];
  const float* proj_w  = (const float*)d_in[11];
  const float* proj_b  = (const float*)d_in[12];
  const float* ln2_g   = (const float*)d_in[13];
  const float* ln2_b   = (const float*)d_in[14];
  const float* fc1_w   = (const float*)d_in[15];
  const float* fc1_b   = (const float*)d_in[16];
  const float* fc2_w   = (const float*)d_in[17];
  const float* fc2_b   = (const float*)d_in[18];
  const float* norm_g  = (const float*)d_in[19];
  const float* norm_b  = (const float*)d_in[20];
  const float* head_w  = (const float*)d_in[21];
  const float* head_b  = (const float*)d_in[22];
  float* out = (float*)d_out;
  (void)in_sizes; (void)n_in; (void)out_size;

  char* cur = (char*)d_ws;
  size_t used = 0;
  auto take = [&](size_t bytes) -> char* {
    char* r = cur;
    size_t pad = (bytes + 255) & ~(size_t)255;
    cur += pad; used += pad;
    return r;
  };
  unsigned short* xp  = (unsigned short*)take((size_t)6272 * 768 * 2);
  float*          t   = (float*)take((size_t)MPAD * 768 * 4);
  unsigned short* h   = (unsigned short*)take((size_t)MPAD * 768 * 2);
  float*          hA  = (float*)take((size_t)MPAD * 8 * 4);
  unsigned short* q   = (unsigned short*)take((size_t)BHD * NPD * HD * 2);
  unsigned short* kk  = (unsigned short*)take((size_t)BHD * NPD * HD * 2);
  unsigned short* vT  = (unsigned short*)take((size_t)BHD * NPD * HD * 2);
  unsigned short* P   = (unsigned short*)take((size_t)BHD * NPD * NPD * 2);
  unsigned short* o   = (unsigned short*)take((size_t)MPAD * 768 * 2);
  unsigned short* g   = (unsigned short*)take((size_t)MPAD * 3072 * 2);
  unsigned short* wpatch = (unsigned short*)take((size_t)768 * 768 * 2);

  const size_t EQKV = (size_t)12 * 2304 * 768, EPROJ = (size_t)12 * 768 * 768,
               EFC1 = (size_t)12 * 3072 * 768, EFC2 = (size_t)12 * 768 * 3072;
  size_t fullBytes = (EQKV + EPROJ + EFC1 + EFC2) * 2 + 4 * 256;
  bool full = (ws_size > used) && (ws_size - used >= fullBytes);
  unsigned short *wqkv = 0, *wproj = 0, *wfc1 = 0, *wfc2 = 0, *wbuf = 0;
  if (full) {
    wqkv  = (unsigned short*)take(EQKV * 2);
    wproj = (unsigned short*)take(EPROJ * 2);
    wfc1  = (unsigned short*)take(EFC1 * 2);
    wfc2  = (unsigned short*)take(EFC2 * 2);
  } else {
    wbuf  = (unsigned short*)take((size_t)3072 * 768 * 2);
  }

  auto cvt = [&](const float* src, unsigned short* dst, size_t n) {
    int n4 = (int)(n / 4);
    int grid = (n4 + 255) / 256; if (grid > 4096) grid = 4096;
    k_cvt<<<grid, 256, 0, stream>>>((const float4*)src, (ushort4*)dst, n4);
  };

  cvt(patch_w, wpatch, (size_t)768 * 768);
  if (full) {
    cvt(qkv_w,  wqkv,  EQKV);
    cvt(proj_w, wproj, EPROJ);
    cvt(fc1_w,  wfc1,  EFC1);
    cvt(fc2_w,  wfc2,  EFC2);
  }

  k_unfold<<<(32 * 196 * 768 + 255) / 256, 256, 0, stream>>>(x, xp);
  k_cls<<<(32 * 768) / 256, 256, 0, stream>>>(cls_tok, pos, t);
  k_patch_gemm<<<dim3(49, 6), 256, 0, stream>>>(xp, wpatch, patch_b, pos, t);

  for (int i = 0; i < 12; ++i) {
    k_ln<<<TOK, 256, 0, stream>>>(t, ln1_g + i * 768, ln1_b + i * 768, h);
    k_lora<<<TOK, 256, 0, stream>>>(h, lora_A + (size_t)i * 768 * 8, hA);
    const unsigned short* wq;
    if (full) wq = wqkv + (size_t)i * 2304 * 768;
    else { cvt(qkv_w + (size_t)i * 2304 * 768, wbuf, (size_t)2304 * 768); wq = wbuf; }
    k_qkv<<<dim3(50, 18), 256, 0, stream>>>(h, wq, qkv_b + (size_t)i * 2304,
                                            hA, lora_B + (size_t)i * 8 * 2304, q, kk, vT);
    k_attn_s<<<dim3(2, BHD), 256, 0, stream>>>(q, kk, P);
    k_attn_pv<<<dim3(2, BHD), 256, 0, stream>>>(P, vT, o);
    const unsigned short* wp;
    if (full) wp = wproj + (size_t)i * 768 * 768;
    else { cvt(proj_w + (size_t)i * 768 * 768, wbuf, (size_t)768 * 768); wp = wbuf; }
    k_proj<<<dim3(50, 6), 256, 0, stream>>>(o, wp, proj_b + (size_t)i * 768, t);
    k_ln<<<TOK, 256, 0, stream>>>(t, ln2_g + i * 768, ln2_b + i * 768, h);
    const unsigned short* w1;
    if (full) w1 = wfc1 + (size_t)i * 3072 * 768;
    else { cvt(fc1_w + (size_t)i * 3072 * 768, wbuf, (size_t)3072 * 768); w1 = wbuf; }
    k_fc1<<<dim3(50, 24), 256, 0, stream>>>(h, w1, fc1_b + (size_t)i * 3072, g);
    const unsigned short* w2;
    if (full) w2 = wfc2 + (size_t)i * 768 * 3072;
    else { cvt(fc2_w + (size_t)i * 768 * 3072, wbuf, (size_t)768 * 3072); w2 = wbuf; }
    k_fc2<<<dim3(50, 6), 256, 0, stream>>>(g, w2, fc2_b + (size_t)i * 768, t);
  }

  k_head<<<32, 256, 0, stream>>>(t, norm_g, norm_b, head_w, head_b, out);
}

// Round 2
// 4499.681 us; speedup vs baseline: 2.7435x; 2.7435x over previous
//
#include <hip/hip_runtime.h>

#define TOK  6304      // 32*197 valid token rows
#define MPAD 6400      // padded rows for 128-tiles
#define NH   12
#define HD   64
#define BHD  384       // 32*12 (b,h) pairs
#define NPD  256       // padded seq per head
#define QKVD 2304

typedef float  f32x4  __attribute__((ext_vector_type(4)));
typedef __bf16 bf16x8 __attribute__((ext_vector_type(8)));

__device__ __forceinline__ unsigned short f2bf(float f) {
  unsigned u = __float_as_uint(f);
  return (unsigned short)((u + 0x7fffu + ((u >> 16) & 1u)) >> 16);
}
__device__ __forceinline__ float bf2f(unsigned short h) {
  return __uint_as_float(((unsigned)h) << 16);
}

__device__ __forceinline__ void gl2lds16(void* g, void* l) {
  __builtin_amdgcn_global_load_lds((__attribute__((address_space(1))) void*)g,
                                   (__attribute__((address_space(3))) void*)l, 16, 0, 0);
}

// NT GEMM core: C[m,n] = sum_k A[m,k]*B[n,k], A/B bf16 K-contiguous.
template<int BM, int BN, int MT, int NT, int WC>
__device__ __forceinline__ void gemm_core(const unsigned short* A, int lda,
                                          const unsigned short* B, int ldb,
                                          int K, int bm, int bn,
                                          unsigned short* lds,
                                          f32x4 (&acc)[MT][NT]) {
  const int tid  = threadIdx.x;
  const int wave = tid >> 6, lane = tid & 63;
  const int wr = wave / WC, wc = wave % WC;
  const int lh = lane >> 4, lm = lane & 15;
  unsigned short* ldsA = lds;
  unsigned short* ldsB = lds + BM * 32;
  constexpr int AIT = BM / 64, BIT = BN / 64;
  for (int k0 = 0; k0 < K; k0 += 32) {
    #pragma unroll
    for (int it = 0; it < AIT; ++it) {
      int idx16 = (wave * AIT + it) * 64 + lane;
      int row = idx16 >> 2, seg = idx16 & 3;
      gl2lds16((void*)(A + (long)(bm + row) * lda + k0 + seg * 8), ldsA + idx16 * 8);
    }
    #pragma unroll
    for (int it = 0; it < BIT; ++it) {
      int idx16 = (wave * BIT + it) * 64 + lane;
      int row = idx16 >> 2, seg = idx16 & 3;
      gl2lds16((void*)(B + (long)(bn + row) * ldb + k0 + seg * 8), ldsB + idx16 * 8);
    }
    __syncthreads();   // drains vmcnt for global_load_lds
    bf16x8 af[MT], bfr[NT];
    #pragma unroll
    for (int i = 0; i < MT; ++i)
      af[i] = *(const bf16x8*)(ldsA + (wr * MT * 16 + i * 16 + lm) * 32 + lh * 8);
    #pragma unroll
    for (int j = 0; j < NT; ++j)
      bfr[j] = *(const bf16x8*)(ldsB + (wc * NT * 16 + j * 16 + lm) * 32 + lh * 8);
    #pragma unroll
    for (int i = 0; i < MT; ++i)
      #pragma unroll
      for (int j = 0; j < NT; ++j)
        acc[i][j] = __builtin_amdgcn_mfma_f32_16x16x32_bf16(af[i], bfr[j], acc[i][j], 0, 0, 0);
    __syncthreads();   // protect LDS before next stage
  }
}

// ---------- small kernels ----------

__global__ __launch_bounds__(256) void k_cvt(const float4* __restrict__ s,
                                             ushort4* __restrict__ d, int n4) {
  int stride = gridDim.x * 256;
  for (int i = blockIdx.x * 256 + threadIdx.x; i < n4; i += stride) {
    float4 v = s[i];
    ushort4 o;
    o.x = f2bf(v.x); o.y = f2bf(v.y); o.z = f2bf(v.z); o.w = f2bf(v.w);
    d[i] = o;
  }
}

__global__ __launch_bounds__(256) void k_unfold(const float* __restrict__ x,
                                                unsigned short* __restrict__ xp) {
  int idx = blockIdx.x * 256 + threadIdx.x;
  if (idx >= 32 * 196 * 768) return;
  int f = idx % 768; int rest = idx / 768;
  int p = rest % 196; int b = rest / 196;
  int c = f >> 8, ij = f & 255, i = ij >> 4, j = ij & 15;
  int py = p / 14, px = p % 14;
  xp[idx] = f2bf(x[(((long)b * 3 + c) * 224 + py * 16 + i) * 224 + px * 16 + j]);
}

__global__ __launch_bounds__(256) void k_cls(const float* __restrict__ cls,
                                             const float* __restrict__ pos,
                                             float* __restrict__ t) {
  int i = blockIdx.x * 256 + threadIdx.x;  // 32*768
  int b = i / 768, d = i % 768;
  t[((long)(b * 197)) * 768 + d] = cls[d] + pos[d];
}

__global__ __launch_bounds__(256) void k_ln(const float* __restrict__ t,
                                            const float* __restrict__ gw,
                                            const float* __restrict__ bw,
                                            unsigned short* __restrict__ h) {
  __shared__ float red[4];
  int row = blockIdx.x, tid = threadIdx.x;
  const float* x = t + (long)row * 768;
  float v0 = x[tid], v1 = x[tid + 256], v2 = x[tid + 512];
  float s = v0 + v1 + v2;
  #pragma unroll
  for (int off = 32; off > 0; off >>= 1) s += __shfl_xor(s, off, 64);
  int wave = tid >> 6, lane = tid & 63;
  if (lane == 0) red[wave] = s;
  __syncthreads();
  s = red[0] + red[1] + red[2] + red[3];
  float mean = s * (1.f / 768.f);
  float d0 = v0 - mean, d1 = v1 - mean, d2 = v2 - mean;
  float s2 = d0 * d0 + d1 * d1 + d2 * d2;
  __syncthreads();
  #pragma unroll
  for (int off = 32; off > 0; off >>= 1) s2 += __shfl_xor(s2, off, 64);
  if (lane == 0) red[wave] = s2;
  __syncthreads();
  s2 = red[0] + red[1] + red[2] + red[3];
  float rstd = rsqrtf(s2 * (1.f / 768.f) + 1e-6f);
  unsigned short* hr = h + (long)row * 768;
  hr[tid]       = f2bf(d0 * rstd * gw[tid]       + bw[tid]);
  hr[tid + 256] = f2bf(d1 * rstd * gw[tid + 256] + bw[tid + 256]);
  hr[tid + 512] = f2bf(d2 * rstd * gw[tid + 512] + bw[tid + 512]);
}

__global__ __launch_bounds__(256) void k_lora(const unsigned short* __restrict__ h,
                                              const float* __restrict__ A,
                                              float* __restrict__ hA) {
  int row = blockIdx.x, tid = threadIdx.x;
  float a[8];
  #pragma unroll
  for (int r = 0; r < 8; ++r) a[r] = 0.f;
  const unsigned short* hr = h + (long)row * 768;
  for (int kx = tid; kx < 768; kx += 256) {
    float hv = bf2f(hr[kx]);
    const float* Ar = A + kx * 8;
    #pragma unroll
    for (int r = 0; r < 8; ++r) a[r] += hv * Ar[r];
  }
  #pragma unroll
  for (int r = 0; r < 8; ++r) {
    #pragma unroll
    for (int off = 32; off > 0; off >>= 1) a[r] += __shfl_xor(a[r], off, 64);
  }
  __shared__ float red[32];
  int wave = tid >> 6, lane = tid & 63;
  if (lane == 0) {
    #pragma unroll
    for (int r = 0; r < 8; ++r) red[wave * 8 + r] = a[r];
  }
  __syncthreads();
  if (tid < 8) hA[(long)row * 8 + tid] = red[tid] + red[8 + tid] + red[16 + tid] + red[24 + tid];
}

__global__ __launch_bounds__(256) void k_head(const float* __restrict__ t,
                                              const float* __restrict__ ng,
                                              const float* __restrict__ nb,
                                              const float* __restrict__ hw,
                                              const float* __restrict__ hb,
                                              float* __restrict__ out) {
  __shared__ float xs[768];
  __shared__ float red[4];
  int b = blockIdx.x, tid = threadIdx.x;
  const float* x = t + ((long)(b * 197)) * 768;
  float v0 = x[tid], v1 = x[tid + 256], v2 = x[tid + 512];
  float s = v0 + v1 + v2;
  #pragma unroll
  for (int off = 32; off > 0; off >>= 1) s += __shfl_xor(s, off, 64);
  int wave = tid >> 6, lane = tid & 63;
  if (lane == 0) red[wave] = s;
  __syncthreads();
  s = red[0] + red[1] + red[2] + red[3];
  float mean = s * (1.f / 768.f);
  float d0 = v0 - mean, d1 = v1 - mean, d2 = v2 - mean;
  float s2 = d0 * d0 + d1 * d1 + d2 * d2;
  __syncthreads();
  #pragma unroll
  for (int off = 32; off > 0; off >>= 1) s2 += __shfl_xor(s2, off, 64);
  if (lane == 0) red[wave] = s2;
  __syncthreads();
  s2 = red[0] + red[1] + red[2] + red[3];
  float rstd = rsqrtf(s2 * (1.f / 768.f) + 1e-6f);
  xs[tid]       = d0 * rstd * ng[tid]       + nb[tid];
  xs[tid + 256] = d1 * rstd * ng[tid + 256] + nb[tid + 256];
  xs[tid + 512] = d2 * rstd * ng[tid + 512] + nb[tid + 512];
  __syncthreads();
  for (int n = tid; n < 100; n += 256) {
    const float* wr = hw + (long)n * 768;
    float acc = hb[n];
    for (int k2 = 0; k2 < 768; ++k2) acc += xs[k2] * wr[k2];
    out[b * 100 + n] = acc;
  }
}

// ---------- GEMM wrappers ----------

__global__ __launch_bounds__(256) void k_patch_gemm(
    const unsigned short* __restrict__ xp, const unsigned short* __restrict__ w,
    const float* __restrict__ bias, const float* __restrict__ pos,
    float* __restrict__ t) {
  __shared__ unsigned short lds[(128 + 128) * 32];
  f32x4 acc[4][4] = {};
  int bm = blockIdx.x * 128, bn = blockIdx.y * 128;
  gemm_core<128, 128, 4, 4, 2>(xp, 768, w, 768, 768, bm, bn, lds, acc);
  const int wave = threadIdx.x >> 6, lane = threadIdx.x & 63;
  const int wr = wave >> 1, wc = wave & 1, lh = lane >> 4, lm = lane & 15;
  #pragma unroll
  for (int i = 0; i < 4; ++i)
  #pragma unroll
  for (int r = 0; r < 4; ++r) {
    int m = bm + wr * 64 + i * 16 + lh * 4 + r;
    int b = m / 196, p = m % 196;
    long trow = ((long)(b * 197 + 1 + p)) * 768;
    #pragma unroll
    for (int j = 0; j < 4; ++j) {
      int n = bn + wc * 64 + j * 16 + lm;
      t[trow + n] = acc[i][j][r] + bias[n] + pos[(1 + p) * 768 + n];
    }
  }
}

__global__ __launch_bounds__(256) void k_qkv(
    const unsigned short* __restrict__ h, const unsigned short* __restrict__ w,
    const float* __restrict__ bias, const float* __restrict__ hA,
    const float* __restrict__ loraB,
    unsigned short* __restrict__ q, unsigned short* __restrict__ kk,
    unsigned short* __restrict__ vT) {
  __shared__ unsigned short lds[(128 + 128) * 32];
  f32x4 acc[4][4] = {};
  int bm = blockIdx.x * 128, bn = blockIdx.y * 128;
  gemm_core<128, 128, 4, 4, 2>(h, 768, w, 768, 768, bm, bn, lds, acc);
  const int wave = threadIdx.x >> 6, lane = threadIdx.x & 63;
  const int wr = wave >> 1, wc = wave & 1, lh = lane >> 4, lm = lane & 15;
  #pragma unroll
  for (int i = 0; i < 4; ++i)
  #pragma unroll
  for (int r = 0; r < 4; ++r) {
    int m = bm + wr * 64 + i * 16 + lh * 4 + r;
    if (m >= TOK) continue;
    int b = m / 197, tok = m % 197;
    const float* ha = hA + (long)m * 8;
    #pragma unroll
    for (int j = 0; j < 4; ++j) {
      int n = bn + wc * 64 + j * 16 + lm;
      float lora = 0.f;
      #pragma unroll
      for (int rr = 0; rr < 8; ++rr) lora += ha[rr] * loraB[rr * QKVD + n];
      float v = acc[i][j][r] + bias[n] + 2.0f * lora;
      int which = n / 768;
      int nr = n - which * 768;
      int hh = nr >> 6, dd = nr & 63;
      long base = (long)(b * NH + hh);
      unsigned short bv = f2bf(v);
      if (which == 0)      q [(base * NPD + tok) * HD + dd] = bv;
      else if (which == 1) kk[(base * NPD + tok) * HD + dd] = bv;
      else                 vT[(base * HD + dd) * NPD + tok] = bv;
    }
  }
}

__global__ __launch_bounds__(256) void k_attn_s(
    const unsigned short* __restrict__ q, const unsigned short* __restrict__ kk,
    unsigned short* __restrict__ P) {
  __shared__ unsigned short lds[(128 + 256) * 32];
  f32x4 acc[2][16] = {};
  int bh = blockIdx.y;
  const unsigned short* Q = q  + (long)bh * NPD * HD;
  const unsigned short* K_ = kk + (long)bh * NPD * HD;
  gemm_core<128, 256, 2, 16, 1>(Q, HD, K_, HD, HD, blockIdx.x * 128, 0, lds, acc);
  const int wave = threadIdx.x >> 6, lane = threadIdx.x & 63;
  const int lh = lane >> 4, lm = lane & 15;
  long Pbase = (long)bh * NPD * NPD;
  #pragma unroll
  for (int i = 0; i < 2; ++i) {
    #pragma unroll
    for (int r = 0; r < 4; ++r) {
      float sv[16]; float mx = -3e38f;
      #pragma unroll
      for (int j = 0; j < 16; ++j) {
        float s = acc[i][j][r] * 0.125f;          // HD^-0.5
        if (j * 16 + lm >= 197) s = -3e38f;       // mask padded keys
        sv[j] = s; mx = fmaxf(mx, s);
      }
      #pragma unroll
      for (int off = 1; off < 16; off <<= 1) mx = fmaxf(mx, __shfl_xor(mx, off, 64));
      float sum = 0.f;
      #pragma unroll
      for (int j = 0; j < 16; ++j) {
        float e = (sv[j] < -1e38f) ? 0.f : __expf(sv[j] - mx);
        sv[j] = e; sum += e;
      }
      #pragma unroll
      for (int off = 1; off < 16; off <<= 1) sum += __shfl_xor(sum, off, 64);
      float inv = 1.f / sum;
      int row = blockIdx.x * 128 + wave * 32 + i * 16 + lh * 4 + r;
      long rowb = Pbase + (long)row * NPD + lm;
      #pragma unroll
      for (int j = 0; j < 16; ++j) P[rowb + j * 16] = f2bf(sv[j] * inv);
    }
  }
}

__global__ __launch_bounds__(256) void k_attn_pv(
    const unsigned short* __restrict__ P, const unsigned short* __restrict__ vT,
    unsigned short* __restrict__ o) {
  __shared__ unsigned short lds[(128 + 64) * 32];
  f32x4 acc[2][4] = {};
  int bh = blockIdx.y;
  int b = bh / NH, hh = bh % NH;
  gemm_core<128, 64, 2, 4, 1>(P + (long)bh * NPD * NPD, NPD,
                              vT + (long)bh * HD * NPD, NPD,
                              NPD, blockIdx.x * 128, 0, lds, acc);
  const int wave = threadIdx.x >> 6, lane = threadIdx.x & 63;
  const int lh = lane >> 4, lm = lane & 15;
  #pragma unroll
  for (int i = 0; i < 2; ++i)
  #pragma unroll
  for (int r = 0; r < 4; ++r) {
    int m = blockIdx.x * 128 + wave * 32 + i * 16 + lh * 4 + r;
    if (m >= 197) continue;
    long ob = ((long)(b * 197 + m)) * 768 + hh * 64;
    #pragma unroll
    for (int j = 0; j < 4; ++j) o[ob + j * 16 + lm] = f2bf(acc[i][j][r]);
  }
}

__global__ __launch_bounds__(256) void k_proj(
    const unsigned short* __restrict__ o, const unsigned short* __restrict__ w,
    const float* __restrict__ bias, float* __restrict__ t) {
  __shared__ unsigned short lds[(128 + 128) * 32];
  f32x4 acc[4][4] = {};
  int bm = blockIdx.x * 128, bn = blockIdx.y * 128;
  gemm_core<128, 128, 4, 4, 2>(o, 768, w, 768, 768, bm, bn, lds, acc);
  const int wave = threadIdx.x >> 6, lane = threadIdx.x & 63;
  const int wr = wave >> 1, wc = wave & 1, lh = lane >> 4, lm = lane & 15;
  #pragma unroll
  for (int i = 0; i < 4; ++i)
  #pragma unroll
  for (int r = 0; r < 4; ++r) {
    int m = bm + wr * 64 + i * 16 + lh * 4 + r;
    if (m >= TOK) continue;
    long trow = (long)m * 768;
    #pragma unroll
    for (int j = 0; j < 4; ++j) {
      int n = bn + wc * 64 + j * 16 + lm;
      t[trow + n] = acc[i][j][r] + bias[n] + t[trow + n];
    }
  }
}

__global__ __launch_bounds__(256) void k_fc1(
    const unsigned short* __restrict__ h, const unsigned short* __restrict__ w,
    const float* __restrict__ bias, unsigned short* __restrict__ g) {
  __shared__ unsigned short lds[(128 + 128) * 32];
  f32x4 acc[4][4] = {};
  int bm = blockIdx.x * 128, bn = blockIdx.y * 128;
  gemm_core<128, 128, 4, 4, 2>(h, 768, w, 768, 768, bm, bn, lds, acc);
  const int wave = threadIdx.x >> 6, lane = threadIdx.x & 63;
  const int wr = wave >> 1, wc = wave & 1, lh = lane >> 4, lm = lane & 15;
  #pragma unroll
  for (int i = 0; i < 4; ++i)
  #pragma unroll
  for (int r = 0; r < 4; ++r) {
    int m = bm + wr * 64 + i * 16 + lh * 4 + r;
    if (m >= TOK) continue;
    long grow = (long)m * 3072;
    #pragma unroll
    for (int j = 0; j < 4; ++j) {
      int n = bn + wc * 64 + j * 16 + lm;
      float u = acc[i][j][r] + bias[n];
      float ge = 0.5f * u * (1.f + erff(u * 0.70710678118654752440f));
      g[grow + n] = f2bf(ge);
    }
  }
}

__global__ __launch_bounds__(256) void k_fc2(
    const unsigned short* __restrict__ g, const unsigned short* __restrict__ w,
    const float* __restrict__ bias, float* __restrict__ t) {
  __shared__ unsigned short lds[(128 + 128) * 32];
  f32x4 acc[4][4] = {};
  int bm = blockIdx.x * 128, bn = blockIdx.y * 128;
  gemm_core<128, 128, 4, 4, 2>(g, 3072, w, 3072, 3072, bm, bn, lds, acc);
  const int wave = threadIdx.x >> 6, lane = threadIdx.x & 63;
  const int wr = wave >> 1, wc = wave & 1, lh = lane >> 4, lm = lane & 15;
  #pragma unroll
  for (int i = 0; i < 4; ++i)
  #pragma unroll
  for (int r = 0; r < 4; ++r) {
    int m = bm + wr * 64 + i * 16 + lh * 4 + r;
    if (m >= TOK) continue;
    long trow = (long)m * 768;
    #pragma unroll
    for (int j = 0; j < 4; ++j) {
      int n = bn + wc * 64 + j * 16 + lm;
      t[trow + n] = acc[i][j][r] + bias[n] + t[trow + n];
    }
  }
}

// ---------- host ----------

extern "C" void kernel_launch(void* const* d_in, const int* in_sizes, int n_in,
                              void* d_out, int out_size, void* d_ws, size_t ws_size,
                              hipStream_t stream) {
  const float* x       = (const float*)d_in[0];
  const float* patch_w = (const float*)d_in[1];
  const float* patch_b = (const float*)d_in[2];
  const float* cls_tok = (const float*)d_in[3];
  const float* pos     = (const float*)d_in[4];
  const float* ln1_g   = (const float*)d_in[5];
  const float* ln1_b   = (const float*)d_in[6];
  const float* qkv_w   = (const float*)d_in[7];
  const float* qkv_b   = (const float*)d_in[8];
  const float* lora_A  = (const float*)d_in[9];
  const float* lora_B  = (const float*)d_in[10];
  const float* proj_w  = (const float*)d_in[11];
  const float* proj_b  = (const float*)d_in[12];
  const float* ln2_g   = (const float*)d_in[13];
  const float* ln2_b   = (const float*)d_in[14];
  const float* fc1_w   = (const float*)d_in[15];
  const float* fc1_b   = (const float*)d_in[16];
  const float* fc2_w   = (const float*)d_in[17];
  const float* fc2_b   = (const float*)d_in[18];
  const float* norm_g  = (const float*)d_in[19];
  const float* norm_b  = (const float*)d_in[20];
  const float* head_w  = (const float*)d_in[21];
  const float* head_b  = (const float*)d_in[22];
  float* out = (float*)d_out;
  (void)in_sizes; (void)n_in; (void)out_size;

  char* cur = (char*)d_ws;
  size_t used = 0;
  auto take = [&](size_t bytes) -> char* {
    char* r = cur;
    size_t pad = (bytes + 255) & ~(size_t)255;
    cur += pad; used += pad;
    return r;
  };
  unsigned short* xp  = (unsigned short*)take((size_t)6272 * 768 * 2);
  float*          t   = (float*)take((size_t)MPAD * 768 * 4);
  unsigned short* h   = (unsigned short*)take((size_t)MPAD * 768 * 2);
  float*          hA  = (float*)take((size_t)MPAD * 8 * 4);
  unsigned short* q   = (unsigned short*)take((size_t)BHD * NPD * HD * 2);
  unsigned short* kk  = (unsigned short*)take((size_t)BHD * NPD * HD * 2);
  unsigned short* vT  = (unsigned short*)take((size_t)BHD * NPD * HD * 2);
  unsigned short* P   = (unsigned short*)take((size_t)BHD * NPD * NPD * 2);
  unsigned short* o   = (unsigned short*)take((size_t)MPAD * 768 * 2);
  unsigned short* g   = (unsigned short*)take((size_t)MPAD * 3072 * 2);
  unsigned short* wpatch = (unsigned short*)take((size_t)768 * 768 * 2);

  const size_t EQKV = (size_t)12 * 2304 * 768, EPROJ = (size_t)12 * 768 * 768,
               EFC1 = (size_t)12 * 3072 * 768, EFC2 = (size_t)12 * 768 * 3072;
  size_t fullBytes = (EQKV + EPROJ + EFC1 + EFC2) * 2 + 4 * 256;
  bool full = (ws_size > used) && (ws_size - used >= fullBytes);
  unsigned short *wqkv = 0, *wproj = 0, *wfc1 = 0, *wfc2 = 0, *wbuf = 0;
  if (full) {
    wqkv  = (unsigned short*)take(EQKV * 2);
    wproj = (unsigned short*)take(EPROJ * 2);
    wfc1  = (unsigned short*)take(EFC1 * 2);
    wfc2  = (unsigned short*)take(EFC2 * 2);
  } else {
    wbuf  = (unsigned short*)take((size_t)3072 * 768 * 2);
  }

  auto cvt = [&](const float* src, unsigned short* dst, size_t n) {
    int n4 = (int)(n / 4);
    int grid = (n4 + 255) / 256; if (grid > 4096) grid = 4096;
    k_cvt<<<grid, 256, 0, stream>>>((const float4*)src, (ushort4*)dst, n4);
  };

  cvt(patch_w, wpatch, (size_t)768 * 768);
  if (full) {
    cvt(qkv_w,  wqkv,  EQKV);
    cvt(proj_w, wproj, EPROJ);
    cvt(fc1_w,  wfc1,  EFC1);
    cvt(fc2_w,  wfc2,  EFC2);
  }

  k_unfold<<<(32 * 196 * 768 + 255) / 256, 256, 0, stream>>>(x, xp);
  k_cls<<<(32 * 768) / 256, 256, 0, stream>>>(cls_tok, pos, t);
  k_patch_gemm<<<dim3(49, 6), 256, 0, stream>>>(xp, wpatch, patch_b, pos, t);

  for (int i = 0; i < 12; ++i) {
    k_ln<<<TOK, 256, 0, stream>>>(t, ln1_g + i * 768, ln1_b + i * 768, h);
    k_lora<<<TOK, 256, 0, stream>>>(h, lora_A + (size_t)i * 768 * 8, hA);
    const unsigned short* wq;
    if (full) wq = wqkv + (size_t)i * 2304 * 768;
    else { cvt(qkv_w + (size_t)i * 2304 * 768, wbuf, (size_t)2304 * 768); wq = wbuf; }
    k_qkv<<<dim3(50, 18), 256, 0, stream>>>(h, wq, qkv_b + (size_t)i * 2304,
                                            hA, lora_B + (size_t)i * 8 * 2304, q, kk, vT);
    k_attn_s<<<dim3(2, BHD), 256, 0, stream>>>(q, kk, P);
    k_attn_pv<<<dim3(2, BHD), 256, 0, stream>>>(P, vT, o);
    const unsigned short* wp;
    if (full) wp = wproj + (size_t)i * 768 * 768;
    else { cvt(proj_w + (size_t)i * 768 * 768, wbuf, (size_t)768 * 768); wp = wbuf; }
    k_proj<<<dim3(50, 6), 256, 0, stream>>>(o, wp, proj_b + (size_t)i * 768, t);
    k_ln<<<TOK, 256, 0, stream>>>(t, ln2_g + i * 768, ln2_b + i * 768, h);
    const unsigned short* w1;
    if (full) w1 = wfc1 + (size_t)i * 3072 * 768;
    else { cvt(fc1_w + (size_t)i * 3072 * 768, wbuf, (size_t)3072 * 768); w1 = wbuf; }
    k_fc1<<<dim3(50, 24), 256, 0, stream>>>(h, w1, fc1_b + (size_t)i * 3072, g);
    const unsigned short* w2;
    if (full) w2 = wfc2 + (size_t)i * 768 * 3072;
    else { cvt(fc2_w + (size_t)i * 768 * 3072, wbuf, (size_t)768 * 3072); w2 = wbuf; }
    k_fc2<<<dim3(50, 6), 256, 0, stream>>>(g, w2, fc2_b + (size_t)i * 768, t);
  }

  k_head<<<32, 256, 0, stream>>>(t, norm_g, norm_b, head_w, head_b, out);
}

// Round 3
// 4023.677 us; speedup vs baseline: 3.0681x; 1.1183x over previous
//
#include <hip/hip_runtime.h>

#define TOK  6304      // 32*197 valid token rows
#define MPAD 6400      // padded rows for 128-tiles
#define NH   12
#define HD   64
#define BHD  384       // 32*12 (b,h) pairs
#define NPD  256       // padded seq per head
#define QKVD 2304
#define PSTR 264       // P LDS row stride (shorts), 264%32dw breaks bank alias

typedef float  f32x4  __attribute__((ext_vector_type(4)));
typedef __bf16 bf16x8 __attribute__((ext_vector_type(8)));

__device__ __forceinline__ unsigned short f2bf(float f) {
  unsigned u = __float_as_uint(f);
  return (unsigned short)((u + 0x7fffu + ((u >> 16) & 1u)) >> 16);
}
__device__ __forceinline__ float bf2f(unsigned short h) {
  return __uint_as_float(((unsigned)h) << 16);
}

__device__ __forceinline__ void gl2lds16(void* g, void* l) {
  __builtin_amdgcn_global_load_lds((__attribute__((address_space(1))) void*)g,
                                   (__attribute__((address_space(3))) void*)l, 16, 0, 0);
}

// NT GEMM core: C[m,n] = sum_k A[m,k]*B[n,k], A/B bf16 K-contiguous.
template<int BM, int BN, int MT, int NT, int WC>
__device__ __forceinline__ void gemm_core(const unsigned short* A, int lda,
                                          const unsigned short* B, int ldb,
                                          int K, int bm, int bn,
                                          unsigned short* lds,
                                          f32x4 (&acc)[MT][NT]) {
  const int tid  = threadIdx.x;
  const int wave = tid >> 6, lane = tid & 63;
  const int wr = wave / WC, wc = wave % WC;
  const int lh = lane >> 4, lm = lane & 15;
  unsigned short* ldsA = lds;
  unsigned short* ldsB = lds + BM * 32;
  constexpr int AIT = BM / 64, BIT = BN / 64;
  for (int k0 = 0; k0 < K; k0 += 32) {
    #pragma unroll
    for (int it = 0; it < AIT; ++it) {
      int idx16 = (wave * AIT + it) * 64 + lane;
      int row = idx16 >> 2, seg = idx16 & 3;
      gl2lds16((void*)(A + (long)(bm + row) * lda + k0 + seg * 8), ldsA + idx16 * 8);
    }
    #pragma unroll
    for (int it = 0; it < BIT; ++it) {
      int idx16 = (wave * BIT + it) * 64 + lane;
      int row = idx16 >> 2, seg = idx16 & 3;
      gl2lds16((void*)(B + (long)(bn + row) * ldb + k0 + seg * 8), ldsB + idx16 * 8);
    }
    __syncthreads();   // drains vmcnt for global_load_lds
    bf16x8 af[MT], bfr[NT];
    #pragma unroll
    for (int i = 0; i < MT; ++i)
      af[i] = *(const bf16x8*)(ldsA + (wr * MT * 16 + i * 16 + lm) * 32 + lh * 8);
    #pragma unroll
    for (int j = 0; j < NT; ++j)
      bfr[j] = *(const bf16x8*)(ldsB + (wc * NT * 16 + j * 16 + lm) * 32 + lh * 8);
    #pragma unroll
    for (int i = 0; i < MT; ++i)
      #pragma unroll
      for (int j = 0; j < NT; ++j)
        acc[i][j] = __builtin_amdgcn_mfma_f32_16x16x32_bf16(af[i], bfr[j], acc[i][j], 0, 0, 0);
    __syncthreads();   // protect LDS before next stage
  }
}

// ---------- small kernels ----------

__global__ __launch_bounds__(256) void k_cvt(const float4* __restrict__ s,
                                             ushort4* __restrict__ d, int n4) {
  int stride = gridDim.x * 256;
  for (int i = blockIdx.x * 256 + threadIdx.x; i < n4; i += stride) {
    float4 v = s[i];
    ushort4 o;
    o.x = f2bf(v.x); o.y = f2bf(v.y); o.z = f2bf(v.z); o.w = f2bf(v.w);
    d[i] = o;
  }
}

__global__ __launch_bounds__(256) void k_unfold(const float* __restrict__ x,
                                                unsigned short* __restrict__ xp) {
  int idx = blockIdx.x * 256 + threadIdx.x;
  if (idx >= 32 * 196 * 768) return;
  int f = idx % 768; int rest = idx / 768;
  int p = rest % 196; int b = rest / 196;
  int c = f >> 8, ij = f & 255, i = ij >> 4, j = ij & 15;
  int py = p / 14, px = p % 14;
  xp[idx] = f2bf(x[(((long)b * 3 + c) * 224 + py * 16 + i) * 224 + px * 16 + j]);
}

__global__ __launch_bounds__(256) void k_cls(const float* __restrict__ cls,
                                             const float* __restrict__ pos,
                                             float* __restrict__ t) {
  int i = blockIdx.x * 256 + threadIdx.x;  // 32*768
  int b = i / 768, d = i % 768;
  t[((long)(b * 197)) * 768 + d] = cls[d] + pos[d];
}

// LayerNorm; if A != nullptr also computes hA[row] = h_f32 @ A (768x8)
__global__ __launch_bounds__(256) void k_ln(const float* __restrict__ t,
                                            const float* __restrict__ gw,
                                            const float* __restrict__ bw,
                                            unsigned short* __restrict__ h,
                                            const float* __restrict__ A,
                                            float* __restrict__ hA) {
  __shared__ float red[4];
  __shared__ float red8[32];
  int row = blockIdx.x, tid = threadIdx.x;
  const float* x = t + (long)row * 768;
  float v0 = x[tid], v1 = x[tid + 256], v2 = x[tid + 512];
  float s = v0 + v1 + v2;
  #pragma unroll
  for (int off = 32; off > 0; off >>= 1) s += __shfl_xor(s, off, 64);
  int wave = tid >> 6, lane = tid & 63;
  if (lane == 0) red[wave] = s;
  __syncthreads();
  s = red[0] + red[1] + red[2] + red[3];
  float mean = s * (1.f / 768.f);
  float d0 = v0 - mean, d1 = v1 - mean, d2 = v2 - mean;
  float s2 = d0 * d0 + d1 * d1 + d2 * d2;
  __syncthreads();
  #pragma unroll
  for (int off = 32; off > 0; off >>= 1) s2 += __shfl_xor(s2, off, 64);
  if (lane == 0) red[wave] = s2;
  __syncthreads();
  s2 = red[0] + red[1] + red[2] + red[3];
  float rstd = rsqrtf(s2 * (1.f / 768.f) + 1e-6f);
  float n0 = d0 * rstd * gw[tid]       + bw[tid];
  float n1 = d1 * rstd * gw[tid + 256] + bw[tid + 256];
  float n2 = d2 * rstd * gw[tid + 512] + bw[tid + 512];
  unsigned short* hr = h + (long)row * 768;
  hr[tid]       = f2bf(n0);
  hr[tid + 256] = f2bf(n1);
  hr[tid + 512] = f2bf(n2);
  if (A) {
    float a[8];
    const float* A0 = A + (long)tid * 8;
    const float* A1 = A + (long)(tid + 256) * 8;
    const float* A2 = A + (long)(tid + 512) * 8;
    #pragma unroll
    for (int rr = 0; rr < 8; ++rr) a[rr] = n0 * A0[rr] + n1 * A1[rr] + n2 * A2[rr];
    #pragma unroll
    for (int rr = 0; rr < 8; ++rr) {
      #pragma unroll
      for (int off = 32; off > 0; off >>= 1) a[rr] += __shfl_xor(a[rr], off, 64);
    }
    if (lane == 0) {
      #pragma unroll
      for (int rr = 0; rr < 8; ++rr) red8[wave * 8 + rr] = a[rr];
    }
    __syncthreads();
    if (tid < 8) hA[(long)row * 8 + tid] = red8[tid] + red8[8 + tid] + red8[16 + tid] + red8[24 + tid];
  }
}

__global__ __launch_bounds__(256) void k_head(const float* __restrict__ t,
                                              const float* __restrict__ ng,
                                              const float* __restrict__ nb,
                                              const float* __restrict__ hw,
                                              const float* __restrict__ hb,
                                              float* __restrict__ out) {
  __shared__ float xs[768];
  __shared__ float red[4];
  int b = blockIdx.x, tid = threadIdx.x;
  const float* x = t + ((long)(b * 197)) * 768;
  float v0 = x[tid], v1 = x[tid + 256], v2 = x[tid + 512];
  float s = v0 + v1 + v2;
  #pragma unroll
  for (int off = 32; off > 0; off >>= 1) s += __shfl_xor(s, off, 64);
  int wave = tid >> 6, lane = tid & 63;
  if (lane == 0) red[wave] = s;
  __syncthreads();
  s = red[0] + red[1] + red[2] + red[3];
  float mean = s * (1.f / 768.f);
  float d0 = v0 - mean, d1 = v1 - mean, d2 = v2 - mean;
  float s2 = d0 * d0 + d1 * d1 + d2 * d2;
  __syncthreads();
  #pragma unroll
  for (int off = 32; off > 0; off >>= 1) s2 += __shfl_xor(s2, off, 64);
  if (lane == 0) red[wave] = s2;
  __syncthreads();
  s2 = red[0] + red[1] + red[2] + red[3];
  float rstd = rsqrtf(s2 * (1.f / 768.f) + 1e-6f);
  xs[tid]       = d0 * rstd * ng[tid]       + nb[tid];
  xs[tid + 256] = d1 * rstd * ng[tid + 256] + nb[tid + 256];
  xs[tid + 512] = d2 * rstd * ng[tid + 512] + nb[tid + 512];
  __syncthreads();
  for (int n = tid; n < 100; n += 256) {
    const float* wr = hw + (long)n * 768;
    float acc = hb[n];
    for (int k2 = 0; k2 < 768; ++k2) acc += xs[k2] * wr[k2];
    out[b * 100 + n] = acc;
  }
}

// ---------- GEMM wrappers ----------

__global__ __launch_bounds__(256) void k_patch_gemm(
    const unsigned short* __restrict__ xp, const unsigned short* __restrict__ w,
    const float* __restrict__ bias, const float* __restrict__ pos,
    float* __restrict__ t) {
  __shared__ unsigned short lds[(128 + 128) * 32];
  f32x4 acc[4][4] = {};
  int bm = blockIdx.x * 128, bn = blockIdx.y * 128;
  gemm_core<128, 128, 4, 4, 2>(xp, 768, w, 768, 768, bm, bn, lds, acc);
  const int wave = threadIdx.x >> 6, lane = threadIdx.x & 63;
  const int wr = wave >> 1, wc = wave & 1, lh = lane >> 4, lm = lane & 15;
  #pragma unroll
  for (int i = 0; i < 4; ++i)
  #pragma unroll
  for (int r = 0; r < 4; ++r) {
    int m = bm + wr * 64 + i * 16 + lh * 4 + r;
    int b = m / 196, p = m % 196;
    long trow = ((long)(b * 197 + 1 + p)) * 768;
    #pragma unroll
    for (int j = 0; j < 4; ++j) {
      int n = bn + wc * 64 + j * 16 + lm;
      t[trow + n] = acc[i][j][r] + bias[n] + pos[(1 + p) * 768 + n];
    }
  }
}

__global__ __launch_bounds__(256) void k_qkv(
    const unsigned short* __restrict__ h, const unsigned short* __restrict__ w,
    const float* __restrict__ bias, const float* __restrict__ hA,
    const float* __restrict__ loraB,
    unsigned short* __restrict__ q, unsigned short* __restrict__ kk,
    unsigned short* __restrict__ vT) {
  __shared__ unsigned short lds[(128 + 128) * 32];
  f32x4 acc[4][4] = {};
  int bm = blockIdx.x * 128, bn = blockIdx.y * 128;
  gemm_core<128, 128, 4, 4, 2>(h, 768, w, 768, 768, bm, bn, lds, acc);
  const int wave = threadIdx.x >> 6, lane = threadIdx.x & 63;
  const int wr = wave >> 1, wc = wave & 1, lh = lane >> 4, lm = lane & 15;
  // hoist the 4 loraB columns this thread needs into registers
  float lb[4][8];
  float bia[4];
  #pragma unroll
  for (int j = 0; j < 4; ++j) {
    int n = bn + wc * 64 + j * 16 + lm;
    bia[j] = bias[n];
    #pragma unroll
    for (int rr = 0; rr < 8; ++rr) lb[j][rr] = loraB[rr * QKVD + n];
  }
  #pragma unroll
  for (int i = 0; i < 4; ++i)
  #pragma unroll
  for (int r = 0; r < 4; ++r) {
    int m = bm + wr * 64 + i * 16 + lh * 4 + r;
    if (m >= TOK) continue;
    int b = m / 197, tok = m % 197;
    const float* ha = hA + (long)m * 8;
    float hv[8];
    #pragma unroll
    for (int rr = 0; rr < 8; ++rr) hv[rr] = ha[rr];   // broadcast loads
    #pragma unroll
    for (int j = 0; j < 4; ++j) {
      int n = bn + wc * 64 + j * 16 + lm;
      float lora = 0.f;
      #pragma unroll
      for (int rr = 0; rr < 8; ++rr) lora += hv[rr] * lb[j][rr];
      float v = acc[i][j][r] + bia[j] + 2.0f * lora;
      int which = n / 768;
      int nr = n - which * 768;
      int hh = nr >> 6, dd = nr & 63;
      long base = (long)(b * NH + hh);
      unsigned short bv = f2bf(v);
      if (which == 0)      q [(base * NPD + tok) * HD + dd] = bv;
      else if (which == 1) kk[(base * NPD + tok) * HD + dd] = bv;
      else                 vT[(base * HD + dd) * NPD + tok] = bv;
    }
  }
}

// Fused attention: S = Q@K^T -> softmax -> P (LDS) -> O = P@V
__global__ __launch_bounds__(256) void k_attn(
    const unsigned short* __restrict__ q, const unsigned short* __restrict__ kk,
    const unsigned short* __restrict__ vT, unsigned short* __restrict__ o) {
  __shared__ unsigned short lds[128 * PSTR + 64 * 32];  // P(67.6KB) + Vstage(4KB)
  f32x4 acc[2][16] = {};
  int bh = blockIdx.y;
  int bm = blockIdx.x * 128;
  gemm_core<128, 256, 2, 16, 1>(q + (long)bh * NPD * HD, HD,
                                kk + (long)bh * NPD * HD, HD, HD, bm, 0, lds, acc);
  const int tid = threadIdx.x, wave = tid >> 6, lane = tid & 63;
  const int lh = lane >> 4, lm = lane & 15;
  unsigned short* Plds = lds;
  #pragma unroll
  for (int i = 0; i < 2; ++i) {
    #pragma unroll
    for (int r = 0; r < 4; ++r) {
      float sv[16]; float mx = -3e38f;
      #pragma unroll
      for (int j = 0; j < 16; ++j) {
        float s = acc[i][j][r] * 0.125f;          // HD^-0.5
        if (j * 16 + lm >= 197) s = -3e38f;       // mask padded keys
        sv[j] = s; mx = fmaxf(mx, s);
      }
      #pragma unroll
      for (int off = 1; off < 16; off <<= 1) mx = fmaxf(mx, __shfl_xor(mx, off, 64));
      float sum = 0.f;
      #pragma unroll
      for (int j = 0; j < 16; ++j) {
        float e = (sv[j] < -1e38f) ? 0.f : __expf(sv[j] - mx);
        sv[j] = e; sum += e;
      }
      #pragma unroll
      for (int off = 1; off < 16; off <<= 1) sum += __shfl_xor(sum, off, 64);
      float inv = 1.f / sum;
      int row = wave * 32 + i * 16 + lh * 4 + r;
      #pragma unroll
      for (int j = 0; j < 16; ++j) Plds[row * PSTR + j * 16 + lm] = f2bf(sv[j] * inv);
    }
  }
  // PV GEMM: A = P (LDS), B = V^T rows=d, K=256 over tokens
  f32x4 acc2[2][4] = {};
  const unsigned short* V = vT + (long)bh * HD * NPD;
  unsigned short* Vst = lds + 128 * PSTR;
  for (int k0 = 0; k0 < NPD; k0 += 32) {
    gl2lds16((void*)(V + (long)(tid >> 2) * NPD + k0 + (tid & 3) * 8), Vst + tid * 8);
    __syncthreads();  // P visible (iter0) + V staged
    bf16x8 af[2], bfr[4];
    #pragma unroll
    for (int i = 0; i < 2; ++i)
      af[i] = *(const bf16x8*)(Plds + (wave * 32 + i * 16 + lm) * PSTR + k0 + lh * 8);
    #pragma unroll
    for (int j = 0; j < 4; ++j)
      bfr[j] = *(const bf16x8*)(Vst + (j * 16 + lm) * 32 + lh * 8);
    #pragma unroll
    for (int i = 0; i < 2; ++i)
      #pragma unroll
      for (int j = 0; j < 4; ++j)
        acc2[i][j] = __builtin_amdgcn_mfma_f32_16x16x32_bf16(af[i], bfr[j], acc2[i][j], 0, 0, 0);
    __syncthreads();
  }
  int b = bh / NH, hh = bh % NH;
  #pragma unroll
  for (int i = 0; i < 2; ++i)
  #pragma unroll
  for (int r = 0; r < 4; ++r) {
    int m = bm + wave * 32 + i * 16 + lh * 4 + r;
    if (m >= 197) continue;
    long ob = ((long)(b * 197 + m)) * 768 + hh * 64;
    #pragma unroll
    for (int j = 0; j < 4; ++j) o[ob + j * 16 + lm] = f2bf(acc2[i][j][r]);
  }
}

__global__ __launch_bounds__(256) void k_proj(
    const unsigned short* __restrict__ o, const unsigned short* __restrict__ w,
    const float* __restrict__ bias, float* __restrict__ t) {
  __shared__ unsigned short lds[(128 + 128) * 32];
  f32x4 acc[4][4] = {};
  int bm = blockIdx.x * 128, bn = blockIdx.y * 128;
  gemm_core<128, 128, 4, 4, 2>(o, 768, w, 768, 768, bm, bn, lds, acc);
  const int wave = threadIdx.x >> 6, lane = threadIdx.x & 63;
  const int wr = wave >> 1, wc = wave & 1, lh = lane >> 4, lm = lane & 15;
  #pragma unroll
  for (int i = 0; i < 4; ++i)
  #pragma unroll
  for (int r = 0; r < 4; ++r) {
    int m = bm + wr * 64 + i * 16 + lh * 4 + r;
    if (m >= TOK) continue;
    long trow = (long)m * 768;
    #pragma unroll
    for (int j = 0; j < 4; ++j) {
      int n = bn + wc * 64 + j * 16 + lm;
      t[trow + n] = acc[i][j][r] + bias[n] + t[trow + n];
    }
  }
}

__global__ __launch_bounds__(256) void k_fc1(
    const unsigned short* __restrict__ h, const unsigned short* __restrict__ w,
    const float* __restrict__ bias, unsigned short* __restrict__ g) {
  __shared__ unsigned short lds[(128 + 128) * 32];
  f32x4 acc[4][4] = {};
  int bm = blockIdx.x * 128, bn = blockIdx.y * 128;
  gemm_core<128, 128, 4, 4, 2>(h, 768, w, 768, 768, bm, bn, lds, acc);
  const int wave = threadIdx.x >> 6, lane = threadIdx.x & 63;
  const int wr = wave >> 1, wc = wave & 1, lh = lane >> 4, lm = lane & 15;
  #pragma unroll
  for (int i = 0; i < 4; ++i)
  #pragma unroll
  for (int r = 0; r < 4; ++r) {
    int m = bm + wr * 64 + i * 16 + lh * 4 + r;
    if (m >= TOK) continue;
    long grow = (long)m * 3072;
    #pragma unroll
    for (int j = 0; j < 4; ++j) {
      int n = bn + wc * 64 + j * 16 + lm;
      float u = acc[i][j][r] + bias[n];
      float ge = 0.5f * u * (1.f + erff(u * 0.70710678118654752440f));
      g[grow + n] = f2bf(ge);
    }
  }
}

__global__ __launch_bounds__(256) void k_fc2(
    const unsigned short* __restrict__ g, const unsigned short* __restrict__ w,
    const float* __restrict__ bias, float* __restrict__ t) {
  __shared__ unsigned short lds[(128 + 128) * 32];
  f32x4 acc[4][4] = {};
  int bm = blockIdx.x * 128, bn = blockIdx.y * 128;
  gemm_core<128, 128, 4, 4, 2>(g, 3072, w, 3072, 3072, bm, bn, lds, acc);
  const int wave = threadIdx.x >> 6, lane = threadIdx.x & 63;
  const int wr = wave >> 1, wc = wave & 1, lh = lane >> 4, lm = lane & 15;
  #pragma unroll
  for (int i = 0; i < 4; ++i)
  #pragma unroll
  for (int r = 0; r < 4; ++r) {
    int m = bm + wr * 64 + i * 16 + lh * 4 + r;
    if (m >= TOK) continue;
    long trow = (long)m * 768;
    #pragma unroll
    for (int j = 0; j < 4; ++j) {
      int n = bn + wc * 64 + j * 16 + lm;
      t[trow + n] = acc[i][j][r] + bias[n] + t[trow + n];
    }
  }
}

// ---------- host ----------

extern "C" void kernel_launch(void* const* d_in, const int* in_sizes, int n_in,
                              void* d_out, int out_size, void* d_ws, size_t ws_size,
                              hipStream_t stream) {
  const float* x       = (const float*)d_in[0];
  const float* patch_w = (const float*)d_in[1];
  const float* patch_b = (const float*)d_in[2];
  const float* cls_tok = (const float*)d_in[3];
  const float* pos     = (const float*)d_in[4];
  const float* ln1_g   = (const float*)d_in[5];
  const float* ln1_b   = (const float*)d_in[6];
  const float* qkv_w   = (const float*)d_in[7];
  const float* qkv_b   = (const float*)d_in[8];
  const float* lora_A  = (const float*)d_in[9];
  const float* lora_B  = (const float*)d_in[10];
  const float* proj_w  = (const float*)d_in[11];
  const float* proj_b  = (const float*)d_in[12];
  const float* ln2_g   = (const float*)d_in[13];
  const float* ln2_b   = (const float*)d_in[14];
  const float* fc1_w   = (const float*)d_in[15];
  const float* fc1_b   = (const float*)d_in[16];
  const float* fc2_w   = (const float*)d_in[17];
  const float* fc2_b   = (const float*)d_in[18];
  const float* norm_g  = (const float*)d_in[19];
  const float* norm_b  = (const float*)d_in[20];
  const float* head_w  = (const float*)d_in[21];
  const float* head_b  = (const float*)d_in[22];
  float* out = (float*)d_out;
  (void)in_sizes; (void)n_in; (void)out_size;

  char* cur = (char*)d_ws;
  size_t used = 0;
  auto take = [&](size_t bytes) -> char* {
    char* r = cur;
    size_t pad = (bytes + 255) & ~(size_t)255;
    cur += pad; used += pad;
    return r;
  };
  unsigned short* xp  = (unsigned short*)take((size_t)6272 * 768 * 2);
  float*          t   = (float*)take((size_t)MPAD * 768 * 4);
  unsigned short* h   = (unsigned short*)take((size_t)MPAD * 768 * 2);
  float*          hA  = (float*)take((size_t)MPAD * 8 * 4);
  unsigned short* q   = (unsigned short*)take((size_t)BHD * NPD * HD * 2);
  unsigned short* kk  = (unsigned short*)take((size_t)BHD * NPD * HD * 2);
  unsigned short* vT  = (unsigned short*)take((size_t)BHD * NPD * HD * 2);
  unsigned short* o   = (unsigned short*)take((size_t)MPAD * 768 * 2);
  unsigned short* g   = (unsigned short*)take((size_t)MPAD * 3072 * 2);
  unsigned short* wpatch = (unsigned short*)take((size_t)768 * 768 * 2);

  const size_t EQKV = (size_t)12 * 2304 * 768, EPROJ = (size_t)12 * 768 * 768,
               EFC1 = (size_t)12 * 3072 * 768, EFC2 = (size_t)12 * 768 * 3072;
  size_t fullBytes = (EQKV + EPROJ + EFC1 + EFC2) * 2 + 4 * 256;
  bool full = (ws_size > used) && (ws_size - used >= fullBytes);
  unsigned short *wqkv = 0, *wproj = 0, *wfc1 = 0, *wfc2 = 0, *wbuf = 0;
  if (full) {
    wqkv  = (unsigned short*)take(EQKV * 2);
    wproj = (unsigned short*)take(EPROJ * 2);
    wfc1  = (unsigned short*)take(EFC1 * 2);
    wfc2  = (unsigned short*)take(EFC2 * 2);
  } else {
    wbuf  = (unsigned short*)take((size_t)3072 * 768 * 2);
  }

  auto cvt = [&](const float* src, unsigned short* dst, size_t n) {
    int n4 = (int)(n / 4);
    int grid = (n4 + 255) / 256; if (grid > 4096) grid = 4096;
    k_cvt<<<grid, 256, 0, stream>>>((const float4*)src, (ushort4*)dst, n4);
  };

  cvt(patch_w, wpatch, (size_t)768 * 768);
  if (full) {
    cvt(qkv_w,  wqkv,  EQKV);
    cvt(proj_w, wproj, EPROJ);
    cvt(fc1_w,  wfc1,  EFC1);
    cvt(fc2_w,  wfc2,  EFC2);
  }

  k_unfold<<<(32 * 196 * 768 + 255) / 256, 256, 0, stream>>>(x, xp);
  k_cls<<<(32 * 768) / 256, 256, 0, stream>>>(cls_tok, pos, t);
  k_patch_gemm<<<dim3(49, 6), 256, 0, stream>>>(xp, wpatch, patch_b, pos, t);

  for (int i = 0; i < 12; ++i) {
    k_ln<<<TOK, 256, 0, stream>>>(t, ln1_g + i * 768, ln1_b + i * 768, h,
                                  lora_A + (size_t)i * 768 * 8, hA);
    const unsigned short* wq;
    if (full) wq = wqkv + (size_t)i * 2304 * 768;
    else { cvt(qkv_w + (size_t)i * 2304 * 768, wbuf, (size_t)2304 * 768); wq = wbuf; }
    k_qkv<<<dim3(50, 18), 256, 0, stream>>>(h, wq, qkv_b + (size_t)i * 2304,
                                            hA, lora_B + (size_t)i * 8 * 2304, q, kk, vT);
    k_attn<<<dim3(2, BHD), 256, 0, stream>>>(q, kk, vT, o);
    const unsigned short* wp;
    if (full) wp = wproj + (size_t)i * 768 * 768;
    else { cvt(proj_w + (size_t)i * 768 * 768, wbuf, (size_t)768 * 768); wp = wbuf; }
    k_proj<<<dim3(50, 6), 256, 0, stream>>>(o, wp, proj_b + (size_t)i * 768, t);
    k_ln<<<TOK, 256, 0, stream>>>(t, ln2_g + i * 768, ln2_b + i * 768, h,
                                  (const float*)nullptr, (float*)nullptr);
    const unsigned short* w1;
    if (full) w1 = wfc1 + (size_t)i * 3072 * 768;
    else { cvt(fc1_w + (size_t)i * 3072 * 768, wbuf, (size_t)3072 * 768); w1 = wbuf; }
    k_fc1<<<dim3(50, 24), 256, 0, stream>>>(h, w1, fc1_b + (size_t)i * 3072, g);
    const unsigned short* w2;
    if (full) w2 = wfc2 + (size_t)i * 768 * 3072;
    else { cvt(fc2_w + (size_t)i * 768 * 3072, wbuf, (size_t)768 * 3072); w2 = wbuf; }
    k_fc2<<<dim3(50, 6), 256, 0, stream>>>(g, w2, fc2_b + (size_t)i * 768, t);
  }

  k_head<<<32, 256, 0, stream>>>(t, norm_g, norm_b, head_w, head_b, out);
}

// Round 4
// 3909.644 us; speedup vs baseline: 3.1575x; 1.0292x over previous
//
#include <hip/hip_runtime.h>

#define TOK  6304      // 32*197 valid token rows
#define MPAD 6400      // padded rows for 128-tiles
#define NH   12
#define HD   64
#define BHD  384       // 32*12 (b,h) pairs
#define NPD  256       // padded seq per head
#define QKVD 2304
#define PSTR 264       // P LDS row stride (shorts); 264/2=132 dw, row stride %32 = 4 -> 2-way

typedef float  f32x4  __attribute__((ext_vector_type(4)));
typedef __bf16 bf16x8 __attribute__((ext_vector_type(8)));

__device__ __forceinline__ unsigned short f2bf(float f) {
  unsigned u = __float_as_uint(f);
  return (unsigned short)((u + 0x7fffu + ((u >> 16) & 1u)) >> 16);
}
__device__ __forceinline__ float bf2f(unsigned short h) {
  return __uint_as_float(((unsigned)h) << 16);
}

__device__ __forceinline__ void gl2lds16(void* g, void* l) {
  __builtin_amdgcn_global_load_lds((__attribute__((address_space(1))) void*)g,
                                   (__attribute__((address_space(3))) void*)l, 16, 0, 0);
}

// NT GEMM core, BK=64, XOR-swizzled LDS (conflict-free ds_read_b128).
// C[m,n] = sum_k A[m,k]*B[n,k]; A/B bf16, K-contiguous, K % 64 == 0.
// Chunk (row,seg) [seg = 16B unit, 8/row] stored at LDS slot row*8 + (seg^(row&7)).
template<int BM, int BN, int MT, int NT, int WC>
__device__ __forceinline__ void gemm64(const unsigned short* A, int lda,
                                       const unsigned short* B, int ldb,
                                       int K, int bm, int bn,
                                       unsigned short* lds,
                                       f32x4 (&acc)[MT][NT]) {
  const int tid  = threadIdx.x;
  const int wave = tid >> 6, lane = tid & 63;
  const int wr = wave / WC, wc = wave % WC;
  const int lh = lane >> 4, lm = lane & 15;
  unsigned short* ldsA = lds;
  unsigned short* ldsB = lds + BM * 64;
  constexpr int AIT = BM * 64 / 2048, BIT = BN * 64 / 2048;
  for (int k0 = 0; k0 < K; k0 += 64) {
    #pragma unroll
    for (int it = 0; it < AIT; ++it) {
      int idx = (wave * AIT + it) * 64 + lane;
      int row = idx >> 3, seg = (idx & 7) ^ (row & 7);
      gl2lds16((void*)(A + (long)(bm + row) * lda + k0 + seg * 8), ldsA + idx * 8);
    }
    #pragma unroll
    for (int it = 0; it < BIT; ++it) {
      int idx = (wave * BIT + it) * 64 + lane;
      int row = idx >> 3, seg = (idx & 7) ^ (row & 7);
      gl2lds16((void*)(B + (long)(bn + row) * ldb + k0 + seg * 8), ldsB + idx * 8);
    }
    __syncthreads();   // drains vmcnt for global_load_lds
    #pragma unroll
    for (int kk2 = 0; kk2 < 2; ++kk2) {
      bf16x8 af[MT], bfr[NT];
      #pragma unroll
      for (int i = 0; i < MT; ++i) {
        int ra = wr * MT * 16 + i * 16 + lm;
        af[i] = *(const bf16x8*)(ldsA + ra * 64 + ((((kk2 << 2) | lh) ^ (ra & 7)) << 3));
      }
      #pragma unroll
      for (int j = 0; j < NT; ++j) {
        int rb = wc * NT * 16 + j * 16 + lm;
        bfr[j] = *(const bf16x8*)(ldsB + rb * 64 + ((((kk2 << 2) | lh) ^ (rb & 7)) << 3));
      }
      #pragma unroll
      for (int i = 0; i < MT; ++i)
        #pragma unroll
        for (int j = 0; j < NT; ++j)
          acc[i][j] = __builtin_amdgcn_mfma_f32_16x16x32_bf16(af[i], bfr[j], acc[i][j], 0, 0, 0);
    }
    __syncthreads();   // protect LDS before next stage
  }
}

// ---------- small kernels ----------

__global__ __launch_bounds__(256) void k_cvt(const float4* __restrict__ s,
                                             ushort4* __restrict__ d, int n4) {
  int stride = gridDim.x * 256;
  for (int i = blockIdx.x * 256 + threadIdx.x; i < n4; i += stride) {
    float4 v = s[i];
    ushort4 o;
    o.x = f2bf(v.x); o.y = f2bf(v.y); o.z = f2bf(v.z); o.w = f2bf(v.w);
    d[i] = o;
  }
}

__global__ __launch_bounds__(256) void k_unfold(const float* __restrict__ x,
                                                unsigned short* __restrict__ xp) {
  int idx = blockIdx.x * 256 + threadIdx.x;
  if (idx >= 32 * 196 * 768) return;
  int f = idx % 768; int rest = idx / 768;
  int p = rest % 196; int b = rest / 196;
  int c = f >> 8, ij = f & 255, i = ij >> 4, j = ij & 15;
  int py = p / 14, px = p % 14;
  xp[idx] = f2bf(x[(((long)b * 3 + c) * 224 + py * 16 + i) * 224 + px * 16 + j]);
}

__global__ __launch_bounds__(256) void k_cls(const float* __restrict__ cls,
                                             const float* __restrict__ pos,
                                             float* __restrict__ t) {
  int i = blockIdx.x * 256 + threadIdx.x;  // 32*768
  int b = i / 768, d = i % 768;
  t[((long)(b * 197)) * 768 + d] = cls[d] + pos[d];
}

// LayerNorm; if A != nullptr also computes hA[row] = h_f32 @ A (768x8)
__global__ __launch_bounds__(256) void k_ln(const float* __restrict__ t,
                                            const float* __restrict__ gw,
                                            const float* __restrict__ bw,
                                            unsigned short* __restrict__ h,
                                            const float* __restrict__ A,
                                            float* __restrict__ hA) {
  __shared__ float red[4];
  __shared__ float red8[32];
  int row = blockIdx.x, tid = threadIdx.x;
  const float* x = t + (long)row * 768;
  float v0 = x[tid], v1 = x[tid + 256], v2 = x[tid + 512];
  float s = v0 + v1 + v2;
  #pragma unroll
  for (int off = 32; off > 0; off >>= 1) s += __shfl_xor(s, off, 64);
  int wave = tid >> 6, lane = tid & 63;
  if (lane == 0) red[wave] = s;
  __syncthreads();
  s = red[0] + red[1] + red[2] + red[3];
  float mean = s * (1.f / 768.f);
  float d0 = v0 - mean, d1 = v1 - mean, d2 = v2 - mean;
  float s2 = d0 * d0 + d1 * d1 + d2 * d2;
  __syncthreads();
  #pragma unroll
  for (int off = 32; off > 0; off >>= 1) s2 += __shfl_xor(s2, off, 64);
  if (lane == 0) red[wave] = s2;
  __syncthreads();
  s2 = red[0] + red[1] + red[2] + red[3];
  float rstd = rsqrtf(s2 * (1.f / 768.f) + 1e-6f);
  float n0 = d0 * rstd * gw[tid]       + bw[tid];
  float n1 = d1 * rstd * gw[tid + 256] + bw[tid + 256];
  float n2 = d2 * rstd * gw[tid + 512] + bw[tid + 512];
  unsigned short* hr = h + (long)row * 768;
  hr[tid]       = f2bf(n0);
  hr[tid + 256] = f2bf(n1);
  hr[tid + 512] = f2bf(n2);
  if (A) {
    float a[8];
    const float* A0 = A + (long)tid * 8;
    const float* A1 = A + (long)(tid + 256) * 8;
    const float* A2 = A + (long)(tid + 512) * 8;
    #pragma unroll
    for (int rr = 0; rr < 8; ++rr) a[rr] = n0 * A0[rr] + n1 * A1[rr] + n2 * A2[rr];
    #pragma unroll
    for (int rr = 0; rr < 8; ++rr) {
      #pragma unroll
      for (int off = 32; off > 0; off >>= 1) a[rr] += __shfl_xor(a[rr], off, 64);
    }
    if (lane == 0) {
      #pragma unroll
      for (int rr = 0; rr < 8; ++rr) red8[wave * 8 + rr] = a[rr];
    }
    __syncthreads();
    if (tid < 8) hA[(long)row * 8 + tid] = red8[tid] + red8[8 + tid] + red8[16 + tid] + red8[24 + tid];
  }
}

__global__ __launch_bounds__(256) void k_head(const float* __restrict__ t,
                                              const float* __restrict__ ng,
                                              const float* __restrict__ nb,
                                              const float* __restrict__ hw,
                                              const float* __restrict__ hb,
                                              float* __restrict__ out) {
  __shared__ float xs[768];
  __shared__ float red[4];
  int b = blockIdx.x, tid = threadIdx.x;
  const float* x = t + ((long)(b * 197)) * 768;
  float v0 = x[tid], v1 = x[tid + 256], v2 = x[tid + 512];
  float s = v0 + v1 + v2;
  #pragma unroll
  for (int off = 32; off > 0; off >>= 1) s += __shfl_xor(s, off, 64);
  int wave = tid >> 6, lane = tid & 63;
  if (lane == 0) red[wave] = s;
  __syncthreads();
  s = red[0] + red[1] + red[2] + red[3];
  float mean = s * (1.f / 768.f);
  float d0 = v0 - mean, d1 = v1 - mean, d2 = v2 - mean;
  float s2 = d0 * d0 + d1 * d1 + d2 * d2;
  __syncthreads();
  #pragma unroll
  for (int off = 32; off > 0; off >>= 1) s2 += __shfl_xor(s2, off, 64);
  if (lane == 0) red[wave] = s2;
  __syncthreads();
  s2 = red[0] + red[1] + red[2] + red[3];
  float rstd = rsqrtf(s2 * (1.f / 768.f) + 1e-6f);
  xs[tid]       = d0 * rstd * ng[tid]       + nb[tid];
  xs[tid + 256] = d1 * rstd * ng[tid + 256] + nb[tid + 256];
  xs[tid + 512] = d2 * rstd * ng[tid + 512] + nb[tid + 512];
  __syncthreads();
  for (int n = tid; n < 100; n += 256) {
    const float* wr = hw + (long)n * 768;
    float acc = hb[n];
    for (int k2 = 0; k2 < 768; ++k2) acc += xs[k2] * wr[k2];
    out[b * 100 + n] = acc;
  }
}

// ---------- GEMM wrappers ----------

__global__ __launch_bounds__(256) void k_patch_gemm(
    const unsigned short* __restrict__ xp, const unsigned short* __restrict__ w,
    const float* __restrict__ bias, const float* __restrict__ pos,
    float* __restrict__ t) {
  __shared__ unsigned short lds[(128 + 128) * 64];
  f32x4 acc[4][4] = {};
  int bm = blockIdx.x * 128, bn = blockIdx.y * 128;
  gemm64<128, 128, 4, 4, 2>(xp, 768, w, 768, 768, bm, bn, lds, acc);
  const int wave = threadIdx.x >> 6, lane = threadIdx.x & 63;
  const int wr = wave >> 1, wc = wave & 1, lh = lane >> 4, lm = lane & 15;
  #pragma unroll
  for (int i = 0; i < 4; ++i)
  #pragma unroll
  for (int r = 0; r < 4; ++r) {
    int m = bm + wr * 64 + i * 16 + lh * 4 + r;
    int b = m / 196, p = m % 196;
    long trow = ((long)(b * 197 + 1 + p)) * 768;
    #pragma unroll
    for (int j = 0; j < 4; ++j) {
      int n = bn + wc * 64 + j * 16 + lm;
      t[trow + n] = acc[i][j][r] + bias[n] + pos[(1 + p) * 768 + n];
    }
  }
}

__global__ __launch_bounds__(256) void k_qkv(
    const unsigned short* __restrict__ h, const unsigned short* __restrict__ w,
    const float* __restrict__ bias, const float* __restrict__ hA,
    const float* __restrict__ loraB,
    unsigned short* __restrict__ q, unsigned short* __restrict__ kk,
    unsigned short* __restrict__ vT) {
  __shared__ unsigned short lds[(128 + 128) * 64];
  f32x4 acc[4][4] = {};
  int bm = blockIdx.x * 128, bn = blockIdx.y * 128;
  gemm64<128, 128, 4, 4, 2>(h, 768, w, 768, 768, bm, bn, lds, acc);
  const int wave = threadIdx.x >> 6, lane = threadIdx.x & 63;
  const int wr = wave >> 1, wc = wave & 1, lh = lane >> 4, lm = lane & 15;
  float lb[4][8];
  float bia[4];
  #pragma unroll
  for (int j = 0; j < 4; ++j) {
    int n = bn + wc * 64 + j * 16 + lm;
    bia[j] = bias[n];
    #pragma unroll
    for (int rr = 0; rr < 8; ++rr) lb[j][rr] = loraB[rr * QKVD + n];
  }
  #pragma unroll
  for (int i = 0; i < 4; ++i)
  #pragma unroll
  for (int r = 0; r < 4; ++r) {
    int m = bm + wr * 64 + i * 16 + lh * 4 + r;
    if (m >= TOK) continue;
    int b = m / 197, tok = m % 197;
    const float* ha = hA + (long)m * 8;
    float hv[8];
    #pragma unroll
    for (int rr = 0; rr < 8; ++rr) hv[rr] = ha[rr];
    #pragma unroll
    for (int j = 0; j < 4; ++j) {
      int n = bn + wc * 64 + j * 16 + lm;
      float lora = 0.f;
      #pragma unroll
      for (int rr = 0; rr < 8; ++rr) lora += hv[rr] * lb[j][rr];
      float v = acc[i][j][r] + bia[j] + 2.0f * lora;
      int which = n / 768;
      int nr = n - which * 768;
      int hh = nr >> 6, dd = nr & 63;
      long base = (long)(b * NH + hh);
      unsigned short bv = f2bf(v);
      if (which == 0)      q [(base * NPD + tok) * HD + dd] = bv;
      else if (which == 1) kk[(base * NPD + tok) * HD + dd] = bv;
      else                 vT[(base * HD + dd) * NPD + tok] = bv;
    }
  }
}

// Fused attention: S = Q@K^T -> softmax -> P (LDS) -> O = P@V
__global__ __launch_bounds__(256) void k_attn(
    const unsigned short* __restrict__ q, const unsigned short* __restrict__ kk,
    const unsigned short* __restrict__ vT, unsigned short* __restrict__ o) {
  // union: S-stage (128+256)*64 = 24576 shorts; P-phase 128*PSTR + 64*64 = 37888 shorts
  __shared__ unsigned short lds[128 * PSTR + 64 * 64];
  f32x4 acc[2][16] = {};
  int bh = blockIdx.y;
  int bm = blockIdx.x * 128;
  gemm64<128, 256, 2, 16, 1>(q + (long)bh * NPD * HD, HD,
                             kk + (long)bh * NPD * HD, HD, HD, bm, 0, lds, acc);
  const int tid = threadIdx.x, wave = tid >> 6, lane = tid & 63;
  const int lh = lane >> 4, lm = lane & 15;
  unsigned short* Plds = lds;
  #pragma unroll
  for (int i = 0; i < 2; ++i) {
    #pragma unroll
    for (int r = 0; r < 4; ++r) {
      float sv[16]; float mx = -3e38f;
      #pragma unroll
      for (int j = 0; j < 16; ++j) {
        float s = acc[i][j][r] * 0.125f;          // HD^-0.5
        if (j * 16 + lm >= 197) s = -3e38f;       // mask padded keys
        sv[j] = s; mx = fmaxf(mx, s);
      }
      #pragma unroll
      for (int off = 1; off < 16; off <<= 1) mx = fmaxf(mx, __shfl_xor(mx, off, 64));
      float sum = 0.f;
      #pragma unroll
      for (int j = 0; j < 16; ++j) {
        float e = (sv[j] < -1e38f) ? 0.f : __expf(sv[j] - mx);
        sv[j] = e; sum += e;
      }
      #pragma unroll
      for (int off = 1; off < 16; off <<= 1) sum += __shfl_xor(sum, off, 64);
      float inv = 1.f / sum;
      int row = wave * 32 + i * 16 + lh * 4 + r;
      #pragma unroll
      for (int j = 0; j < 16; ++j) Plds[row * PSTR + j * 16 + lm] = f2bf(sv[j] * inv);
    }
  }
  // PV GEMM: A = P (padded LDS), B = V^T (swizzled stage), K = 256 tokens
  f32x4 acc2[2][4] = {};
  const unsigned short* V = vT + (long)bh * HD * NPD;
  unsigned short* Vst = lds + 128 * PSTR;
  for (int k0 = 0; k0 < NPD; k0 += 64) {
    #pragma unroll
    for (int it = 0; it < 2; ++it) {
      int idx = (wave * 2 + it) * 64 + lane;
      int row = idx >> 3, seg = (idx & 7) ^ (row & 7);
      gl2lds16((void*)(V + (long)row * NPD + k0 + seg * 8), Vst + idx * 8);
    }
    __syncthreads();  // P visible (iter0) + V staged
    #pragma unroll
    for (int kk2 = 0; kk2 < 2; ++kk2) {
      bf16x8 af[2], bfr[4];
      #pragma unroll
      for (int i = 0; i < 2; ++i)
        af[i] = *(const bf16x8*)(Plds + (wave * 32 + i * 16 + lm) * PSTR + k0 + kk2 * 32 + lh * 8);
      #pragma unroll
      for (int j = 0; j < 4; ++j) {
        int rv = j * 16 + lm;
        bfr[j] = *(const bf16x8*)(Vst + rv * 64 + ((((kk2 << 2) | lh) ^ (rv & 7)) << 3));
      }
      #pragma unroll
      for (int i = 0; i < 2; ++i)
        #pragma unroll
        for (int j = 0; j < 4; ++j)
          acc2[i][j] = __builtin_amdgcn_mfma_f32_16x16x32_bf16(af[i], bfr[j], acc2[i][j], 0, 0, 0);
    }
    __syncthreads();
  }
  int b = bh / NH, hh = bh % NH;
  #pragma unroll
  for (int i = 0; i < 2; ++i)
  #pragma unroll
  for (int r = 0; r < 4; ++r) {
    int m = bm + wave * 32 + i * 16 + lh * 4 + r;
    if (m >= 197) continue;
    long ob = ((long)(b * 197 + m)) * 768 + hh * 64;
    #pragma unroll
    for (int j = 0; j < 4; ++j) o[ob + j * 16 + lm] = f2bf(acc2[i][j][r]);
  }
}

// 64x128 tile (grid 100x6) — occupancy fix for N=768 GEMMs
__global__ __launch_bounds__(256) void k_proj(
    const unsigned short* __restrict__ o, const unsigned short* __restrict__ w,
    const float* __restrict__ bias, float* __restrict__ t) {
  __shared__ unsigned short lds[(64 + 128) * 64];
  f32x4 acc[2][4] = {};
  int bm = blockIdx.x * 64, bn = blockIdx.y * 128;
  gemm64<64, 128, 2, 4, 2>(o, 768, w, 768, 768, bm, bn, lds, acc);
  const int wave = threadIdx.x >> 6, lane = threadIdx.x & 63;
  const int wr = wave >> 1, wc = wave & 1, lh = lane >> 4, lm = lane & 15;
  #pragma unroll
  for (int i = 0; i < 2; ++i)
  #pragma unroll
  for (int r = 0; r < 4; ++r) {
    int m = bm + wr * 32 + i * 16 + lh * 4 + r;
    if (m >= TOK) continue;
    long trow = (long)m * 768;
    #pragma unroll
    for (int j = 0; j < 4; ++j) {
      int n = bn + wc * 64 + j * 16 + lm;
      t[trow + n] = acc[i][j][r] + bias[n] + t[trow + n];
    }
  }
}

__global__ __launch_bounds__(256) void k_fc1(
    const unsigned short* __restrict__ h, const unsigned short* __restrict__ w,
    const float* __restrict__ bias, unsigned short* __restrict__ g) {
  __shared__ unsigned short lds[(128 + 128) * 64];
  f32x4 acc[4][4] = {};
  int bm = blockIdx.x * 128, bn = blockIdx.y * 128;
  gemm64<128, 128, 4, 4, 2>(h, 768, w, 768, 768, bm, bn, lds, acc);
  const int wave = threadIdx.x >> 6, lane = threadIdx.x & 63;
  const int wr = wave >> 1, wc = wave & 1, lh = lane >> 4, lm = lane & 15;
  #pragma unroll
  for (int i = 0; i < 4; ++i)
  #pragma unroll
  for (int r = 0; r < 4; ++r) {
    int m = bm + wr * 64 + i * 16 + lh * 4 + r;
    if (m >= TOK) continue;
    long grow = (long)m * 3072;
    #pragma unroll
    for (int j = 0; j < 4; ++j) {
      int n = bn + wc * 64 + j * 16 + lm;
      float u = acc[i][j][r] + bias[n];
      float ge = 0.5f * u * (1.f + erff(u * 0.70710678118654752440f));
      g[grow + n] = f2bf(ge);
    }
  }
}

// 64x128 tile (grid 100x6)
__global__ __launch_bounds__(256) void k_fc2(
    const unsigned short* __restrict__ g, const unsigned short* __restrict__ w,
    const float* __restrict__ bias, float* __restrict__ t) {
  __shared__ unsigned short lds[(64 + 128) * 64];
  f32x4 acc[2][4] = {};
  int bm = blockIdx.x * 64, bn = blockIdx.y * 128;
  gemm64<64, 128, 2, 4, 2>(g, 3072, w, 3072, 3072, bm, bn, lds, acc);
  const int wave = threadIdx.x >> 6, lane = threadIdx.x & 63;
  const int wr = wave >> 1, wc = wave & 1, lh = lane >> 4, lm = lane & 15;
  #pragma unroll
  for (int i = 0; i < 2; ++i)
  #pragma unroll
  for (int r = 0; r < 4; ++r) {
    int m = bm + wr * 32 + i * 16 + lh * 4 + r;
    if (m >= TOK) continue;
    long trow = (long)m * 768;
    #pragma unroll
    for (int j = 0; j < 4; ++j) {
      int n = bn + wc * 64 + j * 16 + lm;
      t[trow + n] = acc[i][j][r] + bias[n] + t[trow + n];
    }
  }
}

// ---------- host ----------

extern "C" void kernel_launch(void* const* d_in, const int* in_sizes, int n_in,
                              void* d_out, int out_size, void* d_ws, size_t ws_size,
                              hipStream_t stream) {
  const float* x       = (const float*)d_in[0];
  const float* patch_w = (const float*)d_in[1];
  const float* patch_b = (const float*)d_in[2];
  const float* cls_tok = (const float*)d_in[3];
  const float* pos     = (const float*)d_in[4];
  const float* ln1_g   = (const float*)d_in[5];
  const float* ln1_b   = (const float*)d_in[6];
  const float* qkv_w   = (const float*)d_in[7];
  const float* qkv_b   = (const float*)d_in[8];
  const float* lora_A  = (const float*)d_in[9];
  const float* lora_B  = (const float*)d_in[10];
  const float* proj_w  = (const float*)d_in[11];
  const float* proj_b  = (const float*)d_in[12];
  const float* ln2_g   = (const float*)d_in[13];
  const float* ln2_b   = (const float*)d_in[14];
  const float* fc1_w   = (const float*)d_in[15];
  const float* fc1_b   = (const float*)d_in[16];
  const float* fc2_w   = (const float*)d_in[17];
  const float* fc2_b   = (const float*)d_in[18];
  const float* norm_g  = (const float*)d_in[19];
  const float* norm_b  = (const float*)d_in[20];
  const float* head_w  = (const float*)d_in[21];
  const float* head_b  = (const float*)d_in[22];
  float* out = (float*)d_out;
  (void)in_sizes; (void)n_in; (void)out_size;

  char* cur = (char*)d_ws;
  size_t used = 0;
  auto take = [&](size_t bytes) -> char* {
    char* r = cur;
    size_t pad = (bytes + 255) & ~(size_t)255;
    cur += pad; used += pad;
    return r;
  };
  unsigned short* xp  = (unsigned short*)take((size_t)6272 * 768 * 2);
  float*          t   = (float*)take((size_t)MPAD * 768 * 4);
  unsigned short* h   = (unsigned short*)take((size_t)MPAD * 768 * 2);
  float*          hA  = (float*)take((size_t)MPAD * 8 * 4);
  unsigned short* q   = (unsigned short*)take((size_t)BHD * NPD * HD * 2);
  unsigned short* kk  = (unsigned short*)take((size_t)BHD * NPD * HD * 2);
  unsigned short* vT  = (unsigned short*)take((size_t)BHD * NPD * HD * 2);
  unsigned short* o   = (unsigned short*)take((size_t)MPAD * 768 * 2);
  unsigned short* g   = (unsigned short*)take((size_t)MPAD * 3072 * 2);
  unsigned short* wpatch = (unsigned short*)take((size_t)768 * 768 * 2);

  const size_t EQKV = (size_t)12 * 2304 * 768, EPROJ = (size_t)12 * 768 * 768,
               EFC1 = (size_t)12 * 3072 * 768, EFC2 = (size_t)12 * 768 * 3072;
  size_t fullBytes = (EQKV + EPROJ + EFC1 + EFC2) * 2 + 4 * 256;
  bool full = (ws_size > used) && (ws_size - used >= fullBytes);
  unsigned short *wqkv = 0, *wproj = 0, *wfc1 = 0, *wfc2 = 0, *wbuf = 0;
  if (full) {
    wqkv  = (unsigned short*)take(EQKV * 2);
    wproj = (unsigned short*)take(EPROJ * 2);
    wfc1  = (unsigned short*)take(EFC1 * 2);
    wfc2  = (unsigned short*)take(EFC2 * 2);
  } else {
    wbuf  = (unsigned short*)take((size_t)3072 * 768 * 2);
  }

  auto cvt = [&](const float* src, unsigned short* dst, size_t n) {
    int n4 = (int)(n / 4);
    int grid = (n4 + 255) / 256; if (grid > 4096) grid = 4096;
    k_cvt<<<grid, 256, 0, stream>>>((const float4*)src, (ushort4*)dst, n4);
  };

  cvt(patch_w, wpatch, (size_t)768 * 768);
  if (full) {
    cvt(qkv_w,  wqkv,  EQKV);
    cvt(proj_w, wproj, EPROJ);
    cvt(fc1_w,  wfc1,  EFC1);
    cvt(fc2_w,  wfc2,  EFC2);
  }

  k_unfold<<<(32 * 196 * 768 + 255) / 256, 256, 0, stream>>>(x, xp);
  k_cls<<<(32 * 768) / 256, 256, 0, stream>>>(cls_tok, pos, t);
  k_patch_gemm<<<dim3(49, 6), 256, 0, stream>>>(xp, wpatch, patch_b, pos, t);

  for (int i = 0; i < 12; ++i) {
    k_ln<<<TOK, 256, 0, stream>>>(t, ln1_g + i * 768, ln1_b + i * 768, h,
                                  lora_A + (size_t)i * 768 * 8, hA);
    const unsigned short* wq;
    if (full) wq = wqkv + (size_t)i * 2304 * 768;
    else { cvt(qkv_w + (size_t)i * 2304 * 768, wbuf, (size_t)2304 * 768); wq = wbuf; }
    k_qkv<<<dim3(50, 18), 256, 0, stream>>>(h, wq, qkv_b + (size_t)i * 2304,
                                            hA, lora_B + (size_t)i * 8 * 2304, q, kk, vT);
    k_attn<<<dim3(2, BHD), 256, 0, stream>>>(q, kk, vT, o);
    const unsigned short* wp;
    if (full) wp = wproj + (size_t)i * 768 * 768;
    else { cvt(proj_w + (size_t)i * 768 * 768, wbuf, (size_t)768 * 768); wp = wbuf; }
    k_proj<<<dim3(100, 6), 256, 0, stream>>>(o, wp, proj_b + (size_t)i * 768, t);
    k_ln<<<TOK, 256, 0, stream>>>(t, ln2_g + i * 768, ln2_b + i * 768, h,
                                  (const float*)nullptr, (float*)nullptr);
    const unsigned short* w1;
    if (full) w1 = wfc1 + (size_t)i * 3072 * 768;
    else { cvt(fc1_w + (size_t)i * 3072 * 768, wbuf, (size_t)3072 * 768); w1 = wbuf; }
    k_fc1<<<dim3(50, 24), 256, 0, stream>>>(h, w1, fc1_b + (size_t)i * 3072, g);
    const unsigned short* w2;
    if (full) w2 = wfc2 + (size_t)i * 768 * 3072;
    else { cvt(fc2_w + (size_t)i * 768 * 3072, wbuf, (size_t)768 * 3072); w2 = wbuf; }
    k_fc2<<<dim3(100, 6), 256, 0, stream>>>(g, w2, fc2_b + (size_t)i * 768, t);
  }

  k_head<<<32, 256, 0, stream>>>(t, norm_g, norm_b, head_w, head_b, out);
}